// Round 14
// baseline (730.375 us; speedup 1.0000x reference)
//
#include <hip/hip_runtime.h>
#include <math.h>

#define NEGV -1e10f

typedef __bf16 bf16x8 __attribute__((ext_vector_type(8)));
typedef float f32x4 __attribute__((ext_vector_type(4)));
typedef unsigned short ushort;
typedef unsigned int uint;

__device__ __forceinline__ float fast_tanh(float x) {
    float e = __expf(2.0f * x);
    return fmaf(-2.f, __builtin_amdgcn_rcpf(e + 1.f), 1.f);
}
__device__ __forceinline__ float fast_sig(float x) {
    return __builtin_amdgcn_rcpf(1.f + __expf(-x));
}
__device__ __forceinline__ ushort f2bf(float x) {
    unsigned int b = __float_as_uint(x);
    b += 0x7fffu + ((b >> 16) & 1u);   // RNE
    return (ushort)(b >> 16);
}
#if __has_builtin(__builtin_amdgcn_sdot4)
#define SDOT4(a, b, c) __builtin_amdgcn_sdot4((int)(a), (int)(b), (int)(c), false)
#else
__device__ __forceinline__ int SDOT4(int a, int b, int c) {
    #pragma unroll
    for (int k = 0; k < 4; k++) {
        int xa = (a >> (8 * k)) & 0xff; xa = (xa ^ 0x80) - 0x80;
        int xb = (b >> (8 * k)) & 0xff; xb = (xb ^ 0x80) - 0x80;
        c += xa * xb;
    }
    return c;
}
#endif
// async 16B global -> LDS (dest = wave-uniform base + lane*16, src per-lane)
__device__ __forceinline__ void async16(void* l, const void* g) {
    __builtin_amdgcn_global_load_lds(
        (const __attribute__((address_space(1))) void*)g,
        (__attribute__((address_space(3))) void*)l,
        16, 0, 0);
}

// ---------------- dual fp32 -> bf16 cast (both n % 8 == 0) ----------------
__global__ __launch_bounds__(256) void cast2_bf16_kernel(
    const float* __restrict__ inA, const float* __restrict__ inB,
    ushort* __restrict__ outA, ushort* __restrict__ outB, int nA, int nB)
{
    int i = (blockIdx.x * 256 + threadIdx.x) * 8;
    const float* in;
    ushort* out;
    if (i < nA) { in = inA; out = outA; }
    else {
        i -= nA;
        if (i >= nB) return;
        in = inB; out = outB;
    }
    float4 a = *(const float4*)(in + i);
    float4 b = *(const float4*)(in + i + 4);
    uint4 o;
    o.x = (unsigned)f2bf(a.x) | ((unsigned)f2bf(a.y) << 16);
    o.y = (unsigned)f2bf(a.z) | ((unsigned)f2bf(a.w) << 16);
    o.z = (unsigned)f2bf(b.x) | ((unsigned)f2bf(b.y) << 16);
    o.w = (unsigned)f2bf(b.z) | ((unsigned)f2bf(b.w) << 16);
    *(uint4*)(out + i) = o;
}

// ============ prep_all: whh-int8 pack | bias concat | Bp_att | Bp_out | bias_pad ============
// blocks [0,8): per-mat int8 pack, LDS-tiled layout:
//   global dword id j = g*16+jj (gate g, sub jj) of lane l goes to
//   frag8[mat*4096 + (j>>2)*256 + l*4 + (j&3)]  (chunk-major, lane-consecutive 16B)
//   ksc[mat*256 + l*4 + g] = (amax/127)/127
// blocks [8,16): bias_all[(bx-8)*256+tid]
// blocks [16,272): Bp_att rows; [272,400): Bp_out rows; 400: bias_pad
__global__ __launch_bounds__(256) void prep_all_kernel(
    const float* W0, const float* W1, const float* W2, const float* W3,
    const float* W4, const float* W5, const float* W6, const float* W7,
    uint* __restrict__ frag8, float* __restrict__ ksc,
    const float* s0, const float* s1, const float* s2, const float* s3,
    const float* s4, const float* s5, const float* s6, const float* s7,
    float* __restrict__ bias_all,
    const float* __restrict__ Watt_w, ushort* __restrict__ Bp_att,
    const float* __restrict__ out1_w, ushort* __restrict__ Bp_out,
    const float* __restrict__ Watt_b, float* __restrict__ bias_pad)
{
    const int bx = blockIdx.x, tid = threadIdx.x;
    if (bx < 8) {
        const float* Ws[8] = {W0, W1, W2, W3, W4, W5, W6, W7};
        const float* W = Ws[bx];
        int l = tid >> 2, g = tid & 3;
        const float* row = W + (size_t)(g * 64 + l) * 64;
        float amax = 0.f;
        for (int k = 0; k < 64; k++) amax = fmaxf(amax, fabsf(row[k]));
        float sw = fmaxf(amax, 1e-12f) / 127.f;
        float inv = 127.f / fmaxf(amax, 1e-12f);
        ksc[bx * 256 + l * 4 + g] = sw / 127.f;
        for (int jj = 0; jj < 16; jj++) {
            uint wd = 0;
            #pragma unroll
            for (int k = 0; k < 4; k++) {
                int q = __float2int_rn(row[4 * jj + k] * inv);
                q = max(-127, min(127, q));
                wd |= ((uint)(q & 0xff)) << (8 * k);
            }
            int j = g * 16 + jj;
            frag8[bx * 4096 + (j >> 2) * 256 + l * 4 + (j & 3)] = wd;
        }
    } else if (bx < 16) {
        const float* srcs[8] = {s0, s1, s2, s3, s4, s5, s6, s7};
        bias_all[(bx - 8) * 256 + tid] = srcs[bx - 8][tid];
    } else if (bx < 272) {
        int rowi = bx - 16;
        if (tid < 96) {
            float a = 0.f, b = 0.f;
            if (rowi < 132) {
                const float* s = Watt_w + (size_t)rowi * 140;
                if (2 * tid < 140) a = s[2 * tid];
                if (2 * tid + 1 < 140) b = s[2 * tid + 1];
            }
            ((uint*)(Bp_att + (size_t)rowi * 192))[tid] =
                (uint)f2bf(a) | ((uint)f2bf(b) << 16);
        }
    } else if (bx < 400) {
        int rowi = bx - 272;
        if (tid < 96) {
            const float* s = out1_w + (size_t)rowi * 524 + 384;
            float a = (2 * tid < 140) ? s[2 * tid] : 0.f;
            float b = (2 * tid + 1 < 140) ? s[2 * tid + 1] : 0.f;
            ((uint*)(Bp_out + (size_t)rowi * 192))[tid] =
                (uint)f2bf(a) | ((uint)f2bf(b) << 16);
        }
    } else {
        bias_pad[tid] = (tid < 132) ? Watt_b[tid] : 0.f;
    }
}

// =============== shared MFMA GEMM core: C = A[.,K]bf16 @ B[.,K]bf16^T (+bias) ===============
// mode 1: fp32 store, cols < Nstore. mode 2: bf16 store, scan-perm layout
// (col = dir*256+g*64+u -> dir*256 + u*4 + g), ldc elements.
__device__ __forceinline__ void gemm_core(
    const ushort* __restrict__ A, const ushort* __restrict__ B,
    const float* __restrict__ bias, void* __restrict__ C,
    int K, int ldc, int Nstore, int mode, int bm, int bn, ushort* lds)
{
    ushort* ldsA = lds;
    ushort* ldsB = lds + 8192;
    const int tid = threadIdx.x;
    const int wv = tid >> 6, ln = tid & 63;
    const int r15 = ln & 15, r4 = ln >> 4;

    f32x4 acc[4][4] = {};

    for (int k0 = 0; k0 < K; k0 += 64) {
        #pragma unroll
        for (int c4 = 0; c4 < 4; c4++) {
            const int c = c4 * 4 + wv;
            const int s = c * 64 + ln;
            const int rt = s >> 3;
            const int ce = ((s & 7) ^ (rt & 7)) * 8;   // T2 swizzle (both sides)
            async16(&ldsA[c * 512], A + (size_t)(bm + rt) * K + k0 + ce);
            async16(&ldsB[c * 512], B + (size_t)(bn + rt) * K + k0 + ce);
        }
        __syncthreads();
        const int mr = (wv >> 1) * 64, nc = (wv & 1) * 64;
        #pragma unroll
        for (int kk = 0; kk < 2; kk++) {
            bf16x8 af[4], bfr[4];
            #pragma unroll
            for (int m = 0; m < 4; m++) {
                const int r = mr + m * 16 + r15;
                const int off = r * 128 + ((kk * 64 + r4 * 16) ^ ((r & 7) << 4));
                af[m] = *(const bf16x8*)((const char*)ldsA + off);
            }
            #pragma unroll
            for (int n = 0; n < 4; n++) {
                const int r = nc + n * 16 + r15;
                const int off = r * 128 + ((kk * 64 + r4 * 16) ^ ((r & 7) << 4));
                bfr[n] = *(const bf16x8*)((const char*)ldsB + off);
            }
            #pragma unroll
            for (int m = 0; m < 4; m++)
                #pragma unroll
                for (int n = 0; n < 4; n++)
                    acc[m][n] = __builtin_amdgcn_mfma_f32_16x16x32_bf16(
                        af[m], bfr[n], acc[m][n], 0, 0, 0);
        }
        __syncthreads();
    }
    const int mro = bm + (wv >> 1) * 64, nco = bn + (wv & 1) * 64;
    #pragma unroll
    for (int m = 0; m < 4; m++) {
        #pragma unroll
        for (int n = 0; n < 4; n++) {
            const int col = nco + n * 16 + r15;
            const float bs = bias ? bias[col] : 0.f;
            if (mode == 2) {
                const int cout = (col >> 8) * 256 + (col & 63) * 4 + ((col >> 6) & 3);
                #pragma unroll
                for (int r = 0; r < 4; r++) {
                    const int row = mro + m * 16 + r4 * 4 + r;
                    ((ushort*)C)[(size_t)row * ldc + cout] = f2bf(acc[m][n][r] + bs);
                }
            } else if (col < Nstore) {
                #pragma unroll
                for (int r = 0; r < 4; r++) {
                    const int row = mro + m * 16 + r4 * 4 + r;
                    ((float*)C)[(size_t)row * ldc + col] = acc[m][n][r] + bs;
                }
            }
        }
    }
}

// dual-segment GEMM: blockIdx.y < My0 -> segment 0, else segment 1
__global__ __launch_bounds__(256) void gemm_dual_kernel(
    const ushort* A0, const ushort* B0, const float* b0, void* C0, int My0,
    const ushort* A1, const ushort* B1, const float* b1, void* C1,
    int K, int ldc, int Nstore, int mode)
{
    __shared__ __align__(16) ushort smem[16384];
    int by = blockIdx.y;
    if (by < My0)
        gemm_core(A0, B0, b0, C0, K, ldc, Nstore, mode, by * 128, blockIdx.x * 128, smem);
    else
        gemm_core(A1, B1, b1, C1, K, ldc, Nstore, mode, (by - My0) * 128, blockIdx.x * 128, smem);
}

// pair GEMM: bx<2 -> attx (N=132 fp32), bx==2 -> npart (N=128 fp32); shared A
__global__ __launch_bounds__(256) void gemm_pair_kernel(
    const ushort* __restrict__ A,
    const ushort* __restrict__ B0, const float* __restrict__ b0, float* __restrict__ C0,
    const ushort* __restrict__ B1, float* __restrict__ C1, int K)
{
    __shared__ __align__(16) ushort smem[16384];
    if (blockIdx.x < 2)
        gemm_core(A, B0, b0, C0, K, 132, 132, 1, blockIdx.y * 128, blockIdx.x * 128, smem);
    else
        gemm_core(A, B1, nullptr, C1, K, 128, 128, 1, blockIdx.y * 128, 0, smem);
}

// =============== LSTM scan int8 + LDS weights: one wave per (chain,dir) ===============
// R11-R13 established: compiler refuses to keep per-lane weights VGPR-resident and
// reloads them each step (R13: from L1, ~400cy/step of stalls). Fix: stage the 16KB
// weight block in LDS once (global_load_lds), reload in-loop via conflict-free
// ds_read_b128 (lane-consecutive 16B, DS pipe || VALU sdot4s).
// Layout: chunk j4 in [0,16) (gate g=j4>>2, c=j4&3), wlds[j4*256 + l*4 + d] pairs
// with hs[c*4+d]. Two accumulators per gate halve the dot dependency chain.
// proj bf16 [ch][T][dir*256 + u*4 + g]; OBF=1: bf16 out (os elems), else fp32.
template<int OBF>
__global__ __launch_bounds__(64, 1) void lstm_scan_i8(
    const ushort* __restrict__ proj,
    const uint* __restrict__ frag_f, const uint* __restrict__ frag_b,
    const float* __restrict__ ksc_f, const float* __restrict__ ksc_b,
    const int* __restrict__ lengths, void* __restrict__ out,
    int T, int os)
{
    const int ch = blockIdx.x;
    const int dir = blockIdx.y;
    const int l = threadIdx.x;
    const int L = lengths[ch];
    const ushort* projc = proj + (size_t)ch * T * 512 + dir * 256;
    const uint* fragm = dir ? frag_b : frag_f;
    const float4 ks = *(const float4*)((dir ? ksc_b : ksc_f) + l * 4);

    __shared__ __align__(16) uint wlds[4096];   // 16 KB weights
    #pragma unroll
    for (int c = 0; c < 16; c++)
        async16(&wlds[c * 256], fragm + c * 256 + l * 4);
    asm volatile("s_waitcnt vmcnt(0)" ::: "memory");

    int hs[16];
    #pragma unroll
    for (int i = 0; i < 16; i++) hs[i] = 0;

    float cst = 0.f;
    const long od = dir ? -(long)os : (long)os;
    const size_t obase = (size_t)ch * T * os
                       + (size_t)(dir ? (L - 1) : 0) * os + dir * 64 + l;
    float* orow_f = (float*)out + obase;
    ushort* orow_h = (ushort*)out + obase;

    auto ld = [&](int s) -> uint2 {
        int tc = (s < L) ? s : (L - 1);
        int t = dir ? (L - 1 - tc) : tc;
        return *(const uint2*)(projc + (size_t)t * 512 + 4 * l);
    };
    uint2 P0 = ld(0), P1 = ld(1), P2 = ld(2);

    for (int s = 0; s < L; s++) {
        int ai0 = 0, ai1 = 0, af0 = 0, af1 = 0;
        int ag0 = 0, ag1 = 0, ao0 = 0, ao1 = 0;
        #pragma unroll
        for (int c = 0; c < 4; c++) {
            uint4 wi = *(const uint4*)&wlds[(0  + c) * 256 + l * 4];
            uint4 wf = *(const uint4*)&wlds[(4  + c) * 256 + l * 4];
            uint4 wg = *(const uint4*)&wlds[(8  + c) * 256 + l * 4];
            uint4 wo = *(const uint4*)&wlds[(12 + c) * 256 + l * 4];
            const int h0 = hs[c * 4 + 0], h1 = hs[c * 4 + 1];
            const int h2 = hs[c * 4 + 2], h3 = hs[c * 4 + 3];
            ai0 = SDOT4(wi.x, h0, ai0); ai1 = SDOT4(wi.y, h1, ai1);
            ai0 = SDOT4(wi.z, h2, ai0); ai1 = SDOT4(wi.w, h3, ai1);
            af0 = SDOT4(wf.x, h0, af0); af1 = SDOT4(wf.y, h1, af1);
            af0 = SDOT4(wf.z, h2, af0); af1 = SDOT4(wf.w, h3, af1);
            ag0 = SDOT4(wg.x, h0, ag0); ag1 = SDOT4(wg.y, h1, ag1);
            ag0 = SDOT4(wg.z, h2, ag0); ag1 = SDOT4(wg.w, h3, ag1);
            ao0 = SDOT4(wo.x, h0, ao0); ao1 = SDOT4(wo.y, h1, ao1);
            ao0 = SDOT4(wo.z, h2, ao0); ao1 = SDOT4(wo.w, h3, ao1);
        }
        const float pi = __uint_as_float(P0.x << 16);
        const float pf = __uint_as_float(P0.x & 0xffff0000u);
        const float pg = __uint_as_float(P0.y << 16);
        const float po = __uint_as_float(P0.y & 0xffff0000u);
        const float iv = fast_sig(fmaf((float)(ai0 + ai1), ks.x, pi));
        const float fv = fast_sig(fmaf((float)(af0 + af1), ks.y, pf));
        const float gv = fast_tanh(fmaf((float)(ag0 + ag1), ks.z, pg));
        const float ov = fast_sig(fmaf((float)(ao0 + ao1), ks.w, po));
        cst = fmaf(fv, cst, iv * gv);
        const float hv = ov * fast_tanh(cst);

        if (OBF) { *orow_h = f2bf(hv); orow_h += od; }
        else     { *orow_f = hv;       orow_f += od; }

        // h -> int8, pack 4 lanes/dword via 2 shfl_xor, 16 readlane -> SGPRs
        int q8 = __float2int_rn(hv * 127.f);
        int b = q8 & 0xff;
        int t1 = __shfl_xor(b, 1);
        int v01 = (l & 1) ? (t1 | (b << 8)) : (b | (t1 << 8));
        int t2 = __shfl_xor(v01, 2);
        int v0123 = (l & 2) ? ((t2 & 0xffff) | (v01 << 16))
                            : ((v01 & 0xffff) | (t2 << 16));
        #pragma unroll
        for (int i = 0; i < 16; i++)
            hs[i] = __builtin_amdgcn_readlane(v0123, 4 * i);

        P0 = P1; P1 = P2; P2 = ld(s + 3);
    }

    // zero-fill masked region t in [L, T), this direction's 64 cols
    if (OBF) {
        ushort* ob = (ushort*)out + (size_t)ch * T * os + dir * 64;
        for (int idx = l; idx < (T - L) * 64; idx += 64) {
            int t = L + (idx >> 6);
            ob[(size_t)t * os + (idx & 63)] = 0;
        }
    } else {
        float* ob = (float*)out + (size_t)ch * T * os + dir * 64;
        for (int idx = l; idx < (T - L) * 64; idx += 64) {
            int t = L + (idx >> 6);
            ob[(size_t)t * os + (idx & 63)] = 0.f;
        }
    }
}

// ---------------- one-hot + zero pad into A_pad cols 128..191 (bf16) ----------------
__global__ __launch_bounds__(256) void onehot_pad_kernel(
    const int* __restrict__ knowledge, ushort* __restrict__ A_pad)
{
    int row = blockIdx.x * 256 + threadIdx.x;
    if (row >= 96 * 512) return;
    int kn = knowledge[row];
    uint words[8] = {0, 0, 0, 0, 0, 0, 0, 0};
    words[kn >> 1] = (kn & 1) ? 0x3F800000u : 0x00003F80u;   // bf16 1.0
    uint4* dst = (uint4*)(A_pad + (size_t)row * 192 + 128);
    dst[0] = make_uint4(words[0], words[1], words[2], words[3]);
    dst[1] = make_uint4(words[4], words[5], words[6], words[7]);
    uint4 z = make_uint4(0, 0, 0, 0);
    dst[2] = z; dst[3] = z; dst[4] = z; dst[5] = z; dst[6] = z; dst[7] = z;
}

// ---------------- header select + gather: wenc_hs in smem -> hs_ob ----------------
__global__ __launch_bounds__(256) void hs_merge_kernel(
    const float* __restrict__ h1_head, const int* __restrict__ l_hpu,
    const int* __restrict__ knowledge_header,
    const int* __restrict__ wc, const int* __restrict__ wn,
    float* __restrict__ hs_ob)
{
    int b = blockIdx.x, tid = threadIdx.x;
    __shared__ float whs[16][132];
    for (int idx = tid; idx < 16 * 132; idx += 256) {
        int u = idx / 132, c = idx - u * 132;
        int g = b * 16 + u;
        int L = l_hpu[g];
        float v;
        if (c < 128) v = h1_head[((size_t)g * 8 + (L - 1)) * 128 + c];
        else v = ((c - 128) == knowledge_header[g]) ? 1.f : 0.f;
        whs[u][c] = v;
    }
    __syncthreads();
    for (int idx = tid; idx < 4 * 132; idx += 256) {
        int w = idx / 132, c = idx - w * 132;
        int col = (w < wn[b]) ? wc[b * 4 + w] : 0;
        hs_ob[((size_t)b * 4 + w) * 132 + c] = whs[col][c];
    }
}

// ------- fused attention: scores(attx) -> softmax -> context(A_pad) -> vec -------
__global__ __launch_bounds__(256) void att_vec_kernel(
    const float* __restrict__ attx, const float* __restrict__ hs_ob,
    const ushort* __restrict__ A_pad, const int* __restrict__ l_n,
    const float* __restrict__ Wc_w, const float* __restrict__ Wc_b,
    const float* __restrict__ Whs_w, const float* __restrict__ Whs_b,
    const float* __restrict__ Wop_w, const float* __restrict__ Wop_b,
    const int* __restrict__ wn, const int* __restrict__ wo,
    float* __restrict__ vec)
{
    int b = blockIdx.x, w = blockIdx.y;
    int tid = threadIdx.x;
    int L = l_n[b];
    __shared__ float q[132];
    __shared__ float sc[512];
    __shared__ float red[256];
    __shared__ float cn[140];
    if (tid < 132) q[tid] = hs_ob[((size_t)b * 4 + w) * 132 + tid];
    __syncthreads();
    for (int t = tid; t < 512; t += 256) {
        float s = -1e30f;
        if (t < L) {
            const float* ax = attx + ((size_t)b * 512 + t) * 132;
            float s0 = 0.f, s1 = 0.f, s2 = 0.f, s3 = 0.f;
            #pragma unroll
            for (int d = 0; d < 132; d += 4) {
                s0 = fmaf(ax[d + 0], q[d + 0], s0);
                s1 = fmaf(ax[d + 1], q[d + 1], s1);
                s2 = fmaf(ax[d + 2], q[d + 2], s2);
                s3 = fmaf(ax[d + 3], q[d + 3], s3);
            }
            s = (s0 + s1) + (s2 + s3);
        }
        sc[t] = s;
    }
    __syncthreads();
    red[tid] = fmaxf(sc[tid], sc[tid + 256]);
    __syncthreads();
    for (int off = 128; off > 0; off >>= 1) {
        if (tid < off) red[tid] = fmaxf(red[tid], red[tid + off]);
        __syncthreads();
    }
    float m = red[0];
    __syncthreads();
    float ps = 0.f;
    for (int t = tid; t < 512; t += 256) {
        float e = (t < L) ? __expf(sc[t] - m) : 0.f;
        sc[t] = e;
        ps += e;
    }
    red[tid] = ps;
    __syncthreads();
    for (int off = 128; off > 0; off >>= 1) {
        if (tid < off) red[tid] += red[tid + off];
        __syncthreads();
    }
    float inv = 1.f / red[0];
    if (tid < 140) {
        float acc = 0.f;
        const ushort* col = A_pad + (size_t)b * 512 * 192 + tid;
        for (int t = 0; t < L; t++)
            acc = fmaf(sc[t], __uint_as_float((uint)col[(size_t)t * 192] << 16), acc);
        cn[tid] = acc * inv;
    }
    __syncthreads();
    float* vrow = vec + ((size_t)b * 4 + w) * 384;
    if (tid < 128) {
        float acc = Wc_b[tid];
        const float* r = Wc_w + (size_t)tid * 140;
        for (int d = 0; d < 140; d++) acc = fmaf(r[d], cn[d], acc);
        vrow[tid] = acc;
    } else {
        int jj = tid - 128;
        float acc = Whs_b[jj];
        const float* r = Whs_w + (size_t)jj * 132;
        for (int d = 0; d < 132; d++) acc = fmaf(r[d], q[d], acc);
        vrow[128 + jj] = acc;
    }
    if (tid < 128) {
        int op = (w < wn[b]) ? wo[b * 4 + w] : 0;
        vrow[256 + tid] = Wop_b[tid] + Wop_w[tid * 4 + op];
    }
}

// ---------------- SIMT GEMM (vpart): C = A @ B^T (+bias) ----------------
__global__ __launch_bounds__(256) void gemm_bias_kernel(
    const float* __restrict__ A, const float* __restrict__ B,
    const float* __restrict__ bias, float* __restrict__ C,
    int M, int N, int K, int lda, int ldb, int ldc)
{
    __shared__ float As[16][68];
    __shared__ float Bs[16][68];
    const int tid = threadIdx.x;
    const int bm = blockIdx.y * 64;
    const int bn = blockIdx.x * 64;
    const int tx = tid & 15;
    const int ty = tid >> 4;
    const int lm = tid & 63;
    const int lk = (tid >> 6) << 2;
    float acc[4][4] = {};
    const int arow = bm + lm;
    const int brow = bn + lm;

    for (int k0 = 0; k0 < K; k0 += 16) {
        int k = k0 + lk;
        float4 av = make_float4(0.f, 0.f, 0.f, 0.f);
        float4 bv = make_float4(0.f, 0.f, 0.f, 0.f);
        if (arow < M) {
            if (k + 4 <= K) av = *(const float4*)(A + (size_t)arow * lda + k);
            else { float* p = (float*)&av;
                for (int i = 0; i < 4; i++) if (k + i < K) p[i] = A[(size_t)arow * lda + k + i]; }
        }
        if (brow < N) {
            if (k + 4 <= K) bv = *(const float4*)(B + (size_t)brow * ldb + k);
            else { float* p = (float*)&bv;
                for (int i = 0; i < 4; i++) if (k + i < K) p[i] = B[(size_t)brow * ldb + k + i]; }
        }
        As[lk + 0][lm] = av.x; As[lk + 1][lm] = av.y; As[lk + 2][lm] = av.z; As[lk + 3][lm] = av.w;
        Bs[lk + 0][lm] = bv.x; Bs[lk + 1][lm] = bv.y; Bs[lk + 2][lm] = bv.z; Bs[lk + 3][lm] = bv.w;
        __syncthreads();
        #pragma unroll
        for (int kk = 0; kk < 16; kk++) {
            float a[4], bb[4];
            #pragma unroll
            for (int i = 0; i < 4; i++) a[i] = As[kk][ty * 4 + i];
            #pragma unroll
            for (int j = 0; j < 4; j++) bb[j] = Bs[kk][tx * 4 + j];
            #pragma unroll
            for (int i = 0; i < 4; i++)
                #pragma unroll
                for (int j = 0; j < 4; j++)
                    acc[i][j] = fmaf(a[i], bb[j], acc[i][j]);
        }
        __syncthreads();
    }
    #pragma unroll
    for (int i = 0; i < 4; i++) {
        int row = bm + ty * 4 + i;
        if (row >= M) continue;
        #pragma unroll
        for (int j = 0; j < 4; j++) {
            int col = bn + tx * 4 + j;
            if (col < N) C[(size_t)row * ldc + col] = acc[i][j] + (bias ? bias[col] : 0.f);
        }
    }
}

// ---------------- final: out[b,w,t,:] = tanh(vpart+npart)@out2.T + b, masked ----------------
__global__ __launch_bounds__(256) void final_kernel(
    const float* __restrict__ vpart, const float* __restrict__ npart,
    const float* __restrict__ out2_w, const float* __restrict__ out2_b,
    const int* __restrict__ l_n, float* __restrict__ out)
{
    int b = blockIdx.y;
    int tid = threadIdx.x;
    int t = blockIdx.x * 256 + tid;
    __shared__ float vp[512];
    __shared__ float w2[256];
    w2[tid] = out2_w[tid];
    for (int i = tid; i < 512; i += 256) vp[i] = vpart[(size_t)b * 512 + i];
    __syncthreads();
    int L = l_n[b];
    float s[4][2];
    if (t < L) {
        float b0 = out2_b[0], b1 = out2_b[1];
        #pragma unroll
        for (int w = 0; w < 4; w++) { s[w][0] = b0; s[w][1] = b1; }
        const float4* np4 = (const float4*)(npart + ((size_t)b * 512 + t) * 128);
        for (int h4 = 0; h4 < 32; h4++) {
            float4 n = np4[h4];
            const float* nf = (const float*)&n;
            #pragma unroll
            for (int e = 0; e < 4; e++) {
                int h = h4 * 4 + e;
                float nv = nf[e];
                float w0 = w2[h], w1 = w2[128 + h];
                #pragma unroll
                for (int w = 0; w < 4; w++) {
                    float z = fast_tanh(vp[w * 128 + h] + nv);
                    s[w][0] = fmaf(z, w0, s[w][0]);
                    s[w][1] = fmaf(z, w1, s[w][1]);
                }
            }
        }
    } else {
        #pragma unroll
        for (int w = 0; w < 4; w++) { s[w][0] = NEGV; s[w][1] = NEGV; }
    }
    #pragma unroll
    for (int w = 0; w < 4; w++) {
        size_t o = (((size_t)b * 4 + w) * 512 + t) * 2;
        out[o + 0] = s[w][0];
        out[o + 1] = s[w][1];
    }
}

// ---------------------------------------------------------------------------
extern "C" void kernel_launch(void* const* d_in, const int* in_sizes, int n_in,
                              void* d_out, int out_size, void* d_ws, size_t ws_size,
                              hipStream_t stream)
{
    const float* wemb_n   = (const float*)d_in[0];
    const float* wemb_hpu = (const float*)d_in[1];
    const float* Wih_n0f = (const float*)d_in[2];
    const float* Whh_n0f = (const float*)d_in[3];
    const float* b_n0f   = (const float*)d_in[4];
    const float* Wih_n0b = (const float*)d_in[5];
    const float* Whh_n0b = (const float*)d_in[6];
    const float* b_n0b   = (const float*)d_in[7];
    const float* Wih_n1f = (const float*)d_in[8];
    const float* Whh_n1f = (const float*)d_in[9];
    const float* b_n1f   = (const float*)d_in[10];
    const float* Wih_n1b = (const float*)d_in[11];
    const float* Whh_n1b = (const float*)d_in[12];
    const float* b_n1b   = (const float*)d_in[13];
    const float* Wih_h0f = (const float*)d_in[14];
    const float* Whh_h0f = (const float*)d_in[15];
    const float* b_h0f   = (const float*)d_in[16];
    const float* Wih_h0b = (const float*)d_in[17];
    const float* Whh_h0b = (const float*)d_in[18];
    const float* b_h0b   = (const float*)d_in[19];
    const float* Wih_h1f = (const float*)d_in[20];
    const float* Whh_h1f = (const float*)d_in[21];
    const float* b_h1f   = (const float*)d_in[22];
    const float* Wih_h1b = (const float*)d_in[23];
    const float* Whh_h1b = (const float*)d_in[24];
    const float* b_h1b   = (const float*)d_in[25];
    const float* Watt_w  = (const float*)d_in[26];
    const float* Watt_b  = (const float*)d_in[27];
    const float* Wc_w    = (const float*)d_in[28];
    const float* Wc_b    = (const float*)d_in[29];
    const float* Whs_w   = (const float*)d_in[30];
    const float* Whs_b   = (const float*)d_in[31];
    const float* Wop_w   = (const float*)d_in[32];
    const float* Wop_b   = (const float*)d_in[33];
    const float* out1_w  = (const float*)d_in[34];
    const float* out1_b  = (const float*)d_in[35];
    const float* out2_w  = (const float*)d_in[36];
    const float* out2_b  = (const float*)d_in[37];
    const int* l_n   = (const int*)d_in[38];
    const int* l_hpu = (const int*)d_in[39];
    const int* wc    = (const int*)d_in[40];
    const int* wn    = (const int*)d_in[41];
    const int* wo    = (const int*)d_in[42];
    const int* knowledge        = (const int*)d_in[43];
    const int* knowledge_header = (const int*)d_in[44];

    float* ws = (float*)d_ws;
    // ---- workspace map (float offsets; lifetimes annotated) ----
    ushort* proj_q  = (ushort*)(ws + 0);          // [0,12582912)  49152x512 bf16
    ushort* proj_h  = (ushort*)(ws + 12582912);   // [12582912,15728640) 12288x512 bf16
    ushort* AbfH0   = (ushort*)(ws + 15728640);   // wemb_hpu bf16 (dead after G0)
    ushort* A_pad   = (ushort*)(ws + 15728640);   // [49152][192] bf16 (written post-G0)
    ushort* Bp_att  = (ushort*)(ws + 20447232);   // 256x192
    ushort* Bp_out  = (ushort*)(ws + 20471808);   // 128x192
    float*  bias_pad = ws + 20484096;             // 256
    ushort* h_h0_bf = (ushort*)(ws + 22057216);   // 12288x128 bf16
    ushort* WbfQ0   = (ushort*)(ws + 22843648);   // 512x512 bf16
    ushort* WbfH0   = (ushort*)(ws + 22974720);
    ushort* WbfQ1   = (ushort*)(ws + 23105792);   // 512x128
    ushort* WbfH1   = (ushort*)(ws + 23138560);
    uint*   frag8   = (uint*)(ws + 23171328);     // 8 x 4096 dwords int8 Whh (LDS-tiled)
    float*  ksc     = ws + 23204096;              // 8 x 256 scales
    float*  bias_all = ws + 23236864;             // [4][512]
    ushort* AbfQ0   = (ushort*)(ws + 25165824);   // wemb_n bf16 (dead after G0)
    float*  h1_head = ws + 26738688;              // 12288x128 fp32 (post-G0)
    ushort* wenc0_bf = (ushort*)(ws + 31457280);  // 49152x128 bf16 (post-G0)
    float*  attx    = ws + 0;                     // reuse proj_q after QS1
    float*  npart   = ws + 6488064;               // [6488064,12779520)
    float*  hs_ob   = ws + 38541312;
    float*  vec     = ws + 38645760;
    float*  vpart   = ws + 38793216;
    float*  outp    = (float*)d_out;

    dim3 blk(256);
    auto cast2 = [&](const float* a, const float* b, ushort* oa, ushort* ob, int na, int nb) {
        cast2_bf16_kernel<<<dim3(((na + nb) / 8 + 255) / 256), blk, 0, stream>>>(a, b, oa, ob, na, nb);
    };

    // ---- prep + casts ----
    prep_all_kernel<<<dim3(401), blk, 0, stream>>>(
        Whh_n0f, Whh_n0b, Whh_n1f, Whh_n1b, Whh_h0f, Whh_h0b, Whh_h1f, Whh_h1b,
        frag8, ksc,
        b_n0f, b_n0b, b_n1f, b_n1b, b_h0f, b_h0b, b_h1f, b_h1b, bias_all,
        Watt_w, Bp_att, out1_w, Bp_out, Watt_b, bias_pad);
    cast2(wemb_n, wemb_hpu, AbfQ0, AbfH0, 96 * 512 * 512, 1536 * 8 * 512);
    cast2(Wih_n0f, Wih_n0b, WbfQ0, WbfQ0 + 256 * 512, 256 * 512, 256 * 512);
    cast2(Wih_h0f, Wih_h0b, WbfH0, WbfH0 + 256 * 512, 256 * 512, 256 * 512);
    cast2(Wih_n1f, Wih_n1b, WbfQ1, WbfQ1 + 256 * 128, 256 * 128, 256 * 128);
    cast2(Wih_h1f, Wih_h1b, WbfH1, WbfH1 + 256 * 128, 256 * 128, 256 * 128);

    // ---- layer 0 projections (QG0 + HG0 in one dispatch) ----
    gemm_dual_kernel<<<dim3(4, 480), blk, 0, stream>>>(
        AbfQ0, WbfQ0, bias_all + 0 * 512, proj_q, 384,
        AbfH0, WbfH0, bias_all + 2 * 512, proj_h,
        512, 512, 512, 2);
    onehot_pad_kernel<<<dim3(192), blk, 0, stream>>>(knowledge, A_pad);

    // ---- layer-0 scans ----
    lstm_scan_i8<1><<<dim3(96, 2), dim3(64), 0, stream>>>(
        proj_q, frag8 + 0 * 4096, frag8 + 1 * 4096, ksc + 0 * 256, ksc + 1 * 256,
        l_n, wenc0_bf, 512, 128);
    lstm_scan_i8<1><<<dim3(1536, 2), dim3(64), 0, stream>>>(
        proj_h, frag8 + 4 * 4096, frag8 + 5 * 4096, ksc + 4 * 256, ksc + 5 * 256,
        l_hpu, h_h0_bf, 8, 128);

    // ---- layer 1 projections (QG1 + HG1 in one dispatch) ----
    gemm_dual_kernel<<<dim3(4, 480), blk, 0, stream>>>(
        wenc0_bf, WbfQ1, bias_all + 1 * 512, proj_q, 384,
        h_h0_bf, WbfH1, bias_all + 3 * 512, proj_h,
        128, 512, 512, 2);

    // ---- layer-1 scans: QS1 writes A_pad bf16 directly (cols 0..127, stride 192) ----
    lstm_scan_i8<1><<<dim3(96, 2), dim3(64), 0, stream>>>(
        proj_q, frag8 + 2 * 4096, frag8 + 3 * 4096, ksc + 2 * 256, ksc + 3 * 256,
        l_n, A_pad, 512, 192);
    lstm_scan_i8<0><<<dim3(1536, 2), dim3(64), 0, stream>>>(
        proj_h, frag8 + 6 * 4096, frag8 + 7 * 4096, ksc + 6 * 256, ksc + 7 * 256,
        l_hpu, h1_head, 8, 128);

    // ---- tail ----
    hs_merge_kernel<<<dim3(96), blk, 0, stream>>>(h1_head, l_hpu, knowledge_header,
                                                  wc, wn, hs_ob);
    gemm_pair_kernel<<<dim3(3, 384), blk, 0, stream>>>(
        A_pad, Bp_att, bias_pad, attx, Bp_out, npart, 192);
    att_vec_kernel<<<dim3(96, 4), blk, 0, stream>>>(attx, hs_ob, A_pad, l_n,
                                                    Wc_w, Wc_b, Whs_w, Whs_b,
                                                    Wop_w, Wop_b, wn, wo, vec);
    gemm_bias_kernel<<<dim3(2, 6), blk, 0, stream>>>(vec, out1_w, out1_b, vpart,
                                                     384, 128, 384, 384, 524, 128);
    final_kernel<<<dim3(2, 96), blk, 0, stream>>>(vpart, npart, out2_w, out2_b, l_n, outp);
}

// Round 15
// 684.946 us; speedup vs baseline: 1.0663x; 1.0663x over previous
//
#include <hip/hip_runtime.h>
#include <math.h>

#define NEGV -1e10f

typedef __bf16 bf16x8 __attribute__((ext_vector_type(8)));
typedef float f32x4 __attribute__((ext_vector_type(4)));
typedef unsigned short ushort;
typedef unsigned int uint;

__device__ __forceinline__ float fast_tanh(float x) {
    float e = __expf(2.0f * x);
    return fmaf(-2.f, __builtin_amdgcn_rcpf(e + 1.f), 1.f);
}
__device__ __forceinline__ float fast_sig(float x) {
    return __builtin_amdgcn_rcpf(1.f + __expf(-x));
}
__device__ __forceinline__ ushort f2bf(float x) {
    unsigned int b = __float_as_uint(x);
    b += 0x7fffu + ((b >> 16) & 1u);   // RNE
    return (ushort)(b >> 16);
}
#if __has_builtin(__builtin_amdgcn_sdot4)
#define SDOT4(a, b, c) __builtin_amdgcn_sdot4((int)(a), (int)(b), (int)(c), false)
#else
__device__ __forceinline__ int SDOT4(int a, int b, int c) {
    #pragma unroll
    for (int k = 0; k < 4; k++) {
        int xa = (a >> (8 * k)) & 0xff; xa = (xa ^ 0x80) - 0x80;
        int xb = (b >> (8 * k)) & 0xff; xb = (xb ^ 0x80) - 0x80;
        c += xa * xb;
    }
    return c;
}
#endif
// VALU-pipe lane swaps within quads (replaces LDS-pipe ds_swizzle shfl_xor):
// quad_perm[1,0,3,2]=0xB1 (lane^1), quad_perm[2,3,0,1]=0x4E (lane^2)
__device__ __forceinline__ int dpp_xor1(int v) {
    return __builtin_amdgcn_update_dpp(0, v, 0xB1, 0xf, 0xf, true);
}
__device__ __forceinline__ int dpp_xor2(int v) {
    return __builtin_amdgcn_update_dpp(0, v, 0x4E, 0xf, 0xf, true);
}
// async 16B global -> LDS (dest = wave-uniform base + lane*16, src per-lane)
__device__ __forceinline__ void async16(void* l, const void* g) {
    __builtin_amdgcn_global_load_lds(
        (const __attribute__((address_space(1))) void*)g,
        (__attribute__((address_space(3))) void*)l,
        16, 0, 0);
}

// ---------------- dual fp32 -> bf16 cast (both n % 8 == 0) ----------------
__global__ __launch_bounds__(256) void cast2_bf16_kernel(
    const float* __restrict__ inA, const float* __restrict__ inB,
    ushort* __restrict__ outA, ushort* __restrict__ outB, int nA, int nB)
{
    int i = (blockIdx.x * 256 + threadIdx.x) * 8;
    const float* in;
    ushort* out;
    if (i < nA) { in = inA; out = outA; }
    else {
        i -= nA;
        if (i >= nB) return;
        in = inB; out = outB;
    }
    float4 a = *(const float4*)(in + i);
    float4 b = *(const float4*)(in + i + 4);
    uint4 o;
    o.x = (unsigned)f2bf(a.x) | ((unsigned)f2bf(a.y) << 16);
    o.y = (unsigned)f2bf(a.z) | ((unsigned)f2bf(a.w) << 16);
    o.z = (unsigned)f2bf(b.x) | ((unsigned)f2bf(b.y) << 16);
    o.w = (unsigned)f2bf(b.z) | ((unsigned)f2bf(b.w) << 16);
    *(uint4*)(out + i) = o;
}

// ============ prep_all: whh-int8 pack | bias concat | Bp_att | Bp_out | bias_pad ============
// blocks [0,8): per-mat int8 pack (R13 layout: frag8[mat*4096 + l*64 + g*16 + jj])
//   ksc[mat*256 + l*4 + g] = (amax/127)/127
// blocks [8,16): bias_all[(bx-8)*256+tid]
// blocks [16,272): Bp_att rows; [272,400): Bp_out rows; 400: bias_pad
__global__ __launch_bounds__(256) void prep_all_kernel(
    const float* W0, const float* W1, const float* W2, const float* W3,
    const float* W4, const float* W5, const float* W6, const float* W7,
    uint* __restrict__ frag8, float* __restrict__ ksc,
    const float* s0, const float* s1, const float* s2, const float* s3,
    const float* s4, const float* s5, const float* s6, const float* s7,
    float* __restrict__ bias_all,
    const float* __restrict__ Watt_w, ushort* __restrict__ Bp_att,
    const float* __restrict__ out1_w, ushort* __restrict__ Bp_out,
    const float* __restrict__ Watt_b, float* __restrict__ bias_pad)
{
    const int bx = blockIdx.x, tid = threadIdx.x;
    if (bx < 8) {
        const float* Ws[8] = {W0, W1, W2, W3, W4, W5, W6, W7};
        const float* W = Ws[bx];
        int l = tid >> 2, g = tid & 3;
        const float* row = W + (size_t)(g * 64 + l) * 64;
        float amax = 0.f;
        for (int k = 0; k < 64; k++) amax = fmaxf(amax, fabsf(row[k]));
        float sw = fmaxf(amax, 1e-12f) / 127.f;
        float inv = 127.f / fmaxf(amax, 1e-12f);
        ksc[bx * 256 + l * 4 + g] = sw / 127.f;
        uint* dst = frag8 + bx * 4096 + l * 64 + g * 16;
        for (int jj = 0; jj < 16; jj++) {
            uint wd = 0;
            #pragma unroll
            for (int k = 0; k < 4; k++) {
                int q = __float2int_rn(row[4 * jj + k] * inv);
                q = max(-127, min(127, q));
                wd |= ((uint)(q & 0xff)) << (8 * k);
            }
            dst[jj] = wd;
        }
    } else if (bx < 16) {
        const float* srcs[8] = {s0, s1, s2, s3, s4, s5, s6, s7};
        bias_all[(bx - 8) * 256 + tid] = srcs[bx - 8][tid];
    } else if (bx < 272) {
        int rowi = bx - 16;
        if (tid < 96) {
            float a = 0.f, b = 0.f;
            if (rowi < 132) {
                const float* s = Watt_w + (size_t)rowi * 140;
                if (2 * tid < 140) a = s[2 * tid];
                if (2 * tid + 1 < 140) b = s[2 * tid + 1];
            }
            ((uint*)(Bp_att + (size_t)rowi * 192))[tid] =
                (uint)f2bf(a) | ((uint)f2bf(b) << 16);
        }
    } else if (bx < 400) {
        int rowi = bx - 272;
        if (tid < 96) {
            const float* s = out1_w + (size_t)rowi * 524 + 384;
            float a = (2 * tid < 140) ? s[2 * tid] : 0.f;
            float b = (2 * tid + 1 < 140) ? s[2 * tid + 1] : 0.f;
            ((uint*)(Bp_out + (size_t)rowi * 192))[tid] =
                (uint)f2bf(a) | ((uint)f2bf(b) << 16);
        }
    } else {
        bias_pad[tid] = (tid < 132) ? Watt_b[tid] : 0.f;
    }
}

// =============== shared MFMA GEMM core: C = A[.,K]bf16 @ B[.,K]bf16^T (+bias) ===============
// mode 1: fp32 store, cols < Nstore. mode 2: bf16 store, scan-perm layout
// (col = dir*256+g*64+u -> dir*256 + u*4 + g), ldc elements.
__device__ __forceinline__ void gemm_core(
    const ushort* __restrict__ A, const ushort* __restrict__ B,
    const float* __restrict__ bias, void* __restrict__ C,
    int K, int ldc, int Nstore, int mode, int bm, int bn, ushort* lds)
{
    ushort* ldsA = lds;
    ushort* ldsB = lds + 8192;
    const int tid = threadIdx.x;
    const int wv = tid >> 6, ln = tid & 63;
    const int r15 = ln & 15, r4 = ln >> 4;

    f32x4 acc[4][4] = {};

    for (int k0 = 0; k0 < K; k0 += 64) {
        #pragma unroll
        for (int c4 = 0; c4 < 4; c4++) {
            const int c = c4 * 4 + wv;
            const int s = c * 64 + ln;
            const int rt = s >> 3;
            const int ce = ((s & 7) ^ (rt & 7)) * 8;   // T2 swizzle (both sides)
            async16(&ldsA[c * 512], A + (size_t)(bm + rt) * K + k0 + ce);
            async16(&ldsB[c * 512], B + (size_t)(bn + rt) * K + k0 + ce);
        }
        __syncthreads();
        const int mr = (wv >> 1) * 64, nc = (wv & 1) * 64;
        #pragma unroll
        for (int kk = 0; kk < 2; kk++) {
            bf16x8 af[4], bfr[4];
            #pragma unroll
            for (int m = 0; m < 4; m++) {
                const int r = mr + m * 16 + r15;
                const int off = r * 128 + ((kk * 64 + r4 * 16) ^ ((r & 7) << 4));
                af[m] = *(const bf16x8*)((const char*)ldsA + off);
            }
            #pragma unroll
            for (int n = 0; n < 4; n++) {
                const int r = nc + n * 16 + r15;
                const int off = r * 128 + ((kk * 64 + r4 * 16) ^ ((r & 7) << 4));
                bfr[n] = *(const bf16x8*)((const char*)ldsB + off);
            }
            #pragma unroll
            for (int m = 0; m < 4; m++)
                #pragma unroll
                for (int n = 0; n < 4; n++)
                    acc[m][n] = __builtin_amdgcn_mfma_f32_16x16x32_bf16(
                        af[m], bfr[n], acc[m][n], 0, 0, 0);
        }
        __syncthreads();
    }
    const int mro = bm + (wv >> 1) * 64, nco = bn + (wv & 1) * 64;
    #pragma unroll
    for (int m = 0; m < 4; m++) {
        #pragma unroll
        for (int n = 0; n < 4; n++) {
            const int col = nco + n * 16 + r15;
            const float bs = bias ? bias[col] : 0.f;
            if (mode == 2) {
                const int cout = (col >> 8) * 256 + (col & 63) * 4 + ((col >> 6) & 3);
                #pragma unroll
                for (int r = 0; r < 4; r++) {
                    const int row = mro + m * 16 + r4 * 4 + r;
                    ((ushort*)C)[(size_t)row * ldc + cout] = f2bf(acc[m][n][r] + bs);
                }
            } else if (col < Nstore) {
                #pragma unroll
                for (int r = 0; r < 4; r++) {
                    const int row = mro + m * 16 + r4 * 4 + r;
                    ((float*)C)[(size_t)row * ldc + col] = acc[m][n][r] + bs;
                }
            }
        }
    }
}

// dual-segment GEMM: blockIdx.y < My0 -> segment 0, else segment 1
__global__ __launch_bounds__(256) void gemm_dual_kernel(
    const ushort* A0, const ushort* B0, const float* b0, void* C0, int My0,
    const ushort* A1, const ushort* B1, const float* b1, void* C1,
    int K, int ldc, int Nstore, int mode)
{
    __shared__ __align__(16) ushort smem[16384];
    int by = blockIdx.y;
    if (by < My0)
        gemm_core(A0, B0, b0, C0, K, ldc, Nstore, mode, by * 128, blockIdx.x * 128, smem);
    else
        gemm_core(A1, B1, b1, C1, K, ldc, Nstore, mode, (by - My0) * 128, blockIdx.x * 128, smem);
}

// pair GEMM: bx<2 -> attx (N=132 fp32), bx==2 -> npart (N=128 fp32); shared A
__global__ __launch_bounds__(256) void gemm_pair_kernel(
    const ushort* __restrict__ A,
    const ushort* __restrict__ B0, const float* __restrict__ b0, float* __restrict__ C0,
    const ushort* __restrict__ B1, float* __restrict__ C1, int K)
{
    __shared__ __align__(16) ushort smem[16384];
    if (blockIdx.x < 2)
        gemm_core(A, B0, b0, C0, K, 132, 132, 1, blockIdx.y * 128, blockIdx.x * 128, smem);
    else
        gemm_core(A, B1, nullptr, C1, K, 128, 128, 1, blockIdx.y * 128, 0, smem);
}

// =============== LSTM scan int8: one wave per (chain,dir), v_dot4, NO LDS ===============
// R13 structure (weights from global/L1 on the VMEM pipe — R14's LDS staging put
// them on the DS pipe and collided with the shfl swizzles: 199->213us regression).
// NEW: h-redistribution swaps via DPP quad_perm on the VALU pipe (~4cy each)
// instead of 2 serialized ds_swizzle shfl_xor (~100+cy each) - the dominant
// serial-chain component. Dots split into 2 accumulators/gate (8-deep chains).
// proj bf16 [ch][T][dir*256 + u*4 + g]; OBF=1: bf16 out (os elems), else fp32.
template<int OBF>
__global__ __launch_bounds__(64, 1) void lstm_scan_i8(
    const ushort* __restrict__ proj,
    const uint* __restrict__ frag_f, const uint* __restrict__ frag_b,
    const float* __restrict__ ksc_f, const float* __restrict__ ksc_b,
    const int* __restrict__ lengths, void* __restrict__ out,
    int T, int os)
{
    const int ch = blockIdx.x;
    const int dir = blockIdx.y;
    const int l = threadIdx.x;
    const int L = lengths[ch];
    const ushort* projc = proj + (size_t)ch * T * 512 + dir * 256;
    const uint* frag = (dir ? frag_b : frag_f) + (size_t)l * 64;
    const float4 ks = *(const float4*)((dir ? ksc_b : ksc_f) + l * 4);

    uint wq[64];
    #pragma unroll
    for (int i = 0; i < 16; i++) {
        uint4 t4 = *(const uint4*)(frag + i * 4);
        wq[4 * i + 0] = t4.x;
        wq[4 * i + 1] = t4.y;
        wq[4 * i + 2] = t4.z;
        wq[4 * i + 3] = t4.w;
    }

    int hs[16];
    #pragma unroll
    for (int i = 0; i < 16; i++) hs[i] = 0;

    float cst = 0.f;
    const long od = dir ? -(long)os : (long)os;
    const size_t obase = (size_t)ch * T * os
                       + (size_t)(dir ? (L - 1) : 0) * os + dir * 64 + l;
    float* orow_f = (float*)out + obase;
    ushort* orow_h = (ushort*)out + obase;

    auto ld = [&](int s) -> uint2 {
        int tc = (s < L) ? s : (L - 1);
        int t = dir ? (L - 1 - tc) : tc;
        return *(const uint2*)(projc + (size_t)t * 512 + 4 * l);
    };
    uint2 P0 = ld(0), P1 = ld(1), P2 = ld(2);

    for (int s = 0; s < L; s++) {
        int ai0 = 0, ai1 = 0, af0 = 0, af1 = 0;
        int ag0 = 0, ag1 = 0, ao0 = 0, ao1 = 0;
        #pragma unroll
        for (int j = 0; j < 16; j += 2) {
            const int h0 = hs[j], h1 = hs[j + 1];
            ai0 = SDOT4(wq[j],      h0, ai0); ai1 = SDOT4(wq[j + 1],  h1, ai1);
            af0 = SDOT4(wq[16 + j], h0, af0); af1 = SDOT4(wq[17 + j], h1, af1);
            ag0 = SDOT4(wq[32 + j], h0, ag0); ag1 = SDOT4(wq[33 + j], h1, ag1);
            ao0 = SDOT4(wq[48 + j], h0, ao0); ao1 = SDOT4(wq[49 + j], h1, ao1);
        }
        const float pi = __uint_as_float(P0.x << 16);
        const float pf = __uint_as_float(P0.x & 0xffff0000u);
        const float pg = __uint_as_float(P0.y << 16);
        const float po = __uint_as_float(P0.y & 0xffff0000u);
        const float iv = fast_sig(fmaf((float)(ai0 + ai1), ks.x, pi));
        const float fv = fast_sig(fmaf((float)(af0 + af1), ks.y, pf));
        const float gv = fast_tanh(fmaf((float)(ag0 + ag1), ks.z, pg));
        const float ov = fast_sig(fmaf((float)(ao0 + ao1), ks.w, po));
        cst = fmaf(fv, cst, iv * gv);
        const float hv = ov * fast_tanh(cst);

        if (OBF) { *orow_h = f2bf(hv); orow_h += od; }
        else     { *orow_f = hv;       orow_f += od; }

        // h -> int8, pack 4 lanes/dword via 2 DPP quad_perm swaps (VALU pipe),
        // then 16 readlane -> SGPR broadcast
        int q8 = __float2int_rn(hv * 127.f);
        int b = q8 & 0xff;
        int t1 = dpp_xor1(b);
        int v01 = (l & 1) ? (t1 | (b << 8)) : (b | (t1 << 8));
        int t2 = dpp_xor2(v01);
        int v0123 = (l & 2) ? ((t2 & 0xffff) | (v01 << 16))
                            : ((v01 & 0xffff) | (t2 << 16));
        #pragma unroll
        for (int i = 0; i < 16; i++)
            hs[i] = __builtin_amdgcn_readlane(v0123, 4 * i);

        P0 = P1; P1 = P2; P2 = ld(s + 3);
    }

    // zero-fill masked region t in [L, T), this direction's 64 cols
    if (OBF) {
        ushort* ob = (ushort*)out + (size_t)ch * T * os + dir * 64;
        for (int idx = l; idx < (T - L) * 64; idx += 64) {
            int t = L + (idx >> 6);
            ob[(size_t)t * os + (idx & 63)] = 0;
        }
    } else {
        float* ob = (float*)out + (size_t)ch * T * os + dir * 64;
        for (int idx = l; idx < (T - L) * 64; idx += 64) {
            int t = L + (idx >> 6);
            ob[(size_t)t * os + (idx & 63)] = 0.f;
        }
    }
}

// ---------------- one-hot + zero pad into A_pad cols 128..191 (bf16) ----------------
__global__ __launch_bounds__(256) void onehot_pad_kernel(
    const int* __restrict__ knowledge, ushort* __restrict__ A_pad)
{
    int row = blockIdx.x * 256 + threadIdx.x;
    if (row >= 96 * 512) return;
    int kn = knowledge[row];
    uint words[8] = {0, 0, 0, 0, 0, 0, 0, 0};
    words[kn >> 1] = (kn & 1) ? 0x3F800000u : 0x00003F80u;   // bf16 1.0
    uint4* dst = (uint4*)(A_pad + (size_t)row * 192 + 128);
    dst[0] = make_uint4(words[0], words[1], words[2], words[3]);
    dst[1] = make_uint4(words[4], words[5], words[6], words[7]);
    uint4 z = make_uint4(0, 0, 0, 0);
    dst[2] = z; dst[3] = z; dst[4] = z; dst[5] = z; dst[6] = z; dst[7] = z;
}

// ---------------- header select + gather: wenc_hs in smem -> hs_ob ----------------
__global__ __launch_bounds__(256) void hs_merge_kernel(
    const float* __restrict__ h1_head, const int* __restrict__ l_hpu,
    const int* __restrict__ knowledge_header,
    const int* __restrict__ wc, const int* __restrict__ wn,
    float* __restrict__ hs_ob)
{
    int b = blockIdx.x, tid = threadIdx.x;
    __shared__ float whs[16][132];
    for (int idx = tid; idx < 16 * 132; idx += 256) {
        int u = idx / 132, c = idx - u * 132;
        int g = b * 16 + u;
        int L = l_hpu[g];
        float v;
        if (c < 128) v = h1_head[((size_t)g * 8 + (L - 1)) * 128 + c];
        else v = ((c - 128) == knowledge_header[g]) ? 1.f : 0.f;
        whs[u][c] = v;
    }
    __syncthreads();
    for (int idx = tid; idx < 4 * 132; idx += 256) {
        int w = idx / 132, c = idx - w * 132;
        int col = (w < wn[b]) ? wc[b * 4 + w] : 0;
        hs_ob[((size_t)b * 4 + w) * 132 + c] = whs[col][c];
    }
}

// ------- fused attention: scores(attx) -> softmax -> context(A_pad) -> vec -------
__global__ __launch_bounds__(256) void att_vec_kernel(
    const float* __restrict__ attx, const float* __restrict__ hs_ob,
    const ushort* __restrict__ A_pad, const int* __restrict__ l_n,
    const float* __restrict__ Wc_w, const float* __restrict__ Wc_b,
    const float* __restrict__ Whs_w, const float* __restrict__ Whs_b,
    const float* __restrict__ Wop_w, const float* __restrict__ Wop_b,
    const int* __restrict__ wn, const int* __restrict__ wo,
    float* __restrict__ vec)
{
    int b = blockIdx.x, w = blockIdx.y;
    int tid = threadIdx.x;
    int L = l_n[b];
    __shared__ float q[132];
    __shared__ float sc[512];
    __shared__ float red[256];
    __shared__ float cn[140];
    if (tid < 132) q[tid] = hs_ob[((size_t)b * 4 + w) * 132 + tid];
    __syncthreads();
    for (int t = tid; t < 512; t += 256) {
        float s = -1e30f;
        if (t < L) {
            const float* ax = attx + ((size_t)b * 512 + t) * 132;
            float s0 = 0.f, s1 = 0.f, s2 = 0.f, s3 = 0.f;
            #pragma unroll
            for (int d = 0; d < 132; d += 4) {
                s0 = fmaf(ax[d + 0], q[d + 0], s0);
                s1 = fmaf(ax[d + 1], q[d + 1], s1);
                s2 = fmaf(ax[d + 2], q[d + 2], s2);
                s3 = fmaf(ax[d + 3], q[d + 3], s3);
            }
            s = (s0 + s1) + (s2 + s3);
        }
        sc[t] = s;
    }
    __syncthreads();
    red[tid] = fmaxf(sc[tid], sc[tid + 256]);
    __syncthreads();
    for (int off = 128; off > 0; off >>= 1) {
        if (tid < off) red[tid] = fmaxf(red[tid], red[tid + off]);
        __syncthreads();
    }
    float m = red[0];
    __syncthreads();
    float ps = 0.f;
    for (int t = tid; t < 512; t += 256) {
        float e = (t < L) ? __expf(sc[t] - m) : 0.f;
        sc[t] = e;
        ps += e;
    }
    red[tid] = ps;
    __syncthreads();
    for (int off = 128; off > 0; off >>= 1) {
        if (tid < off) red[tid] += red[tid + off];
        __syncthreads();
    }
    float inv = 1.f / red[0];
    if (tid < 140) {
        float acc = 0.f;
        const ushort* col = A_pad + (size_t)b * 512 * 192 + tid;
        for (int t = 0; t < L; t++)
            acc = fmaf(sc[t], __uint_as_float((uint)col[(size_t)t * 192] << 16), acc);
        cn[tid] = acc * inv;
    }
    __syncthreads();
    float* vrow = vec + ((size_t)b * 4 + w) * 384;
    if (tid < 128) {
        float acc = Wc_b[tid];
        const float* r = Wc_w + (size_t)tid * 140;
        for (int d = 0; d < 140; d++) acc = fmaf(r[d], cn[d], acc);
        vrow[tid] = acc;
    } else {
        int jj = tid - 128;
        float acc = Whs_b[jj];
        const float* r = Whs_w + (size_t)jj * 132;
        for (int d = 0; d < 132; d++) acc = fmaf(r[d], q[d], acc);
        vrow[128 + jj] = acc;
    }
    if (tid < 128) {
        int op = (w < wn[b]) ? wo[b * 4 + w] : 0;
        vrow[256 + tid] = Wop_b[tid] + Wop_w[tid * 4 + op];
    }
}

// ---------------- SIMT GEMM (vpart): C = A @ B^T (+bias) ----------------
__global__ __launch_bounds__(256) void gemm_bias_kernel(
    const float* __restrict__ A, const float* __restrict__ B,
    const float* __restrict__ bias, float* __restrict__ C,
    int M, int N, int K, int lda, int ldb, int ldc)
{
    __shared__ float As[16][68];
    __shared__ float Bs[16][68];
    const int tid = threadIdx.x;
    const int bm = blockIdx.y * 64;
    const int bn = blockIdx.x * 64;
    const int tx = tid & 15;
    const int ty = tid >> 4;
    const int lm = tid & 63;
    const int lk = (tid >> 6) << 2;
    float acc[4][4] = {};
    const int arow = bm + lm;
    const int brow = bn + lm;

    for (int k0 = 0; k0 < K; k0 += 16) {
        int k = k0 + lk;
        float4 av = make_float4(0.f, 0.f, 0.f, 0.f);
        float4 bv = make_float4(0.f, 0.f, 0.f, 0.f);
        if (arow < M) {
            if (k + 4 <= K) av = *(const float4*)(A + (size_t)arow * lda + k);
            else { float* p = (float*)&av;
                for (int i = 0; i < 4; i++) if (k + i < K) p[i] = A[(size_t)arow * lda + k + i]; }
        }
        if (brow < N) {
            if (k + 4 <= K) bv = *(const float4*)(B + (size_t)brow * ldb + k);
            else { float* p = (float*)&bv;
                for (int i = 0; i < 4; i++) if (k + i < K) p[i] = B[(size_t)brow * ldb + k + i]; }
        }
        As[lk + 0][lm] = av.x; As[lk + 1][lm] = av.y; As[lk + 2][lm] = av.z; As[lk + 3][lm] = av.w;
        Bs[lk + 0][lm] = bv.x; Bs[lk + 1][lm] = bv.y; Bs[lk + 2][lm] = bv.z; Bs[lk + 3][lm] = bv.w;
        __syncthreads();
        #pragma unroll
        for (int kk = 0; kk < 16; kk++) {
            float a[4], bb[4];
            #pragma unroll
            for (int i = 0; i < 4; i++) a[i] = As[kk][ty * 4 + i];
            #pragma unroll
            for (int j = 0; j < 4; j++) bb[j] = Bs[kk][tx * 4 + j];
            #pragma unroll
            for (int i = 0; i < 4; i++)
                #pragma unroll
                for (int j = 0; j < 4; j++)
                    acc[i][j] = fmaf(a[i], bb[j], acc[i][j]);
        }
        __syncthreads();
    }
    #pragma unroll
    for (int i = 0; i < 4; i++) {
        int row = bm + ty * 4 + i;
        if (row >= M) continue;
        #pragma unroll
        for (int j = 0; j < 4; j++) {
            int col = bn + tx * 4 + j;
            if (col < N) C[(size_t)row * ldc + col] = acc[i][j] + (bias ? bias[col] : 0.f);
        }
    }
}

// ---------------- final: out[b,w,t,:] = tanh(vpart+npart)@out2.T + b, masked ----------------
__global__ __launch_bounds__(256) void final_kernel(
    const float* __restrict__ vpart, const float* __restrict__ npart,
    const float* __restrict__ out2_w, const float* __restrict__ out2_b,
    const int* __restrict__ l_n, float* __restrict__ out)
{
    int b = blockIdx.y;
    int tid = threadIdx.x;
    int t = blockIdx.x * 256 + tid;
    __shared__ float vp[512];
    __shared__ float w2[256];
    w2[tid] = out2_w[tid];
    for (int i = tid; i < 512; i += 256) vp[i] = vpart[(size_t)b * 512 + i];
    __syncthreads();
    int L = l_n[b];
    float s[4][2];
    if (t < L) {
        float b0 = out2_b[0], b1 = out2_b[1];
        #pragma unroll
        for (int w = 0; w < 4; w++) { s[w][0] = b0; s[w][1] = b1; }
        const float4* np4 = (const float4*)(npart + ((size_t)b * 512 + t) * 128);
        for (int h4 = 0; h4 < 32; h4++) {
            float4 n = np4[h4];
            const float* nf = (const float*)&n;
            #pragma unroll
            for (int e = 0; e < 4; e++) {
                int h = h4 * 4 + e;
                float nv = nf[e];
                float w0 = w2[h], w1 = w2[128 + h];
                #pragma unroll
                for (int w = 0; w < 4; w++) {
                    float z = fast_tanh(vp[w * 128 + h] + nv);
                    s[w][0] = fmaf(z, w0, s[w][0]);
                    s[w][1] = fmaf(z, w1, s[w][1]);
                }
            }
        }
    } else {
        #pragma unroll
        for (int w = 0; w < 4; w++) { s[w][0] = NEGV; s[w][1] = NEGV; }
    }
    #pragma unroll
    for (int w = 0; w < 4; w++) {
        size_t o = (((size_t)b * 4 + w) * 512 + t) * 2;
        out[o + 0] = s[w][0];
        out[o + 1] = s[w][1];
    }
}

// ---------------------------------------------------------------------------
extern "C" void kernel_launch(void* const* d_in, const int* in_sizes, int n_in,
                              void* d_out, int out_size, void* d_ws, size_t ws_size,
                              hipStream_t stream)
{
    const float* wemb_n   = (const float*)d_in[0];
    const float* wemb_hpu = (const float*)d_in[1];
    const float* Wih_n0f = (const float*)d_in[2];
    const float* Whh_n0f = (const float*)d_in[3];
    const float* b_n0f   = (const float*)d_in[4];
    const float* Wih_n0b = (const float*)d_in[5];
    const float* Whh_n0b = (const float*)d_in[6];
    const float* b_n0b   = (const float*)d_in[7];
    const float* Wih_n1f = (const float*)d_in[8];
    const float* Whh_n1f = (const float*)d_in[9];
    const float* b_n1f   = (const float*)d_in[10];
    const float* Wih_n1b = (const float*)d_in[11];
    const float* Whh_n1b = (const float*)d_in[12];
    const float* b_n1b   = (const float*)d_in[13];
    const float* Wih_h0f = (const float*)d_in[14];
    const float* Whh_h0f = (const float*)d_in[15];
    const float* b_h0f   = (const float*)d_in[16];
    const float* Wih_h0b = (const float*)d_in[17];
    const float* Whh_h0b = (const float*)d_in[18];
    const float* b_h0b   = (const float*)d_in[19];
    const float* Wih_h1f = (const float*)d_in[20];
    const float* Whh_h1f = (const float*)d_in[21];
    const float* b_h1f   = (const float*)d_in[22];
    const float* Wih_h1b = (const float*)d_in[23];
    const float* Whh_h1b = (const float*)d_in[24];
    const float* b_h1b   = (const float*)d_in[25];
    const float* Watt_w  = (const float*)d_in[26];
    const float* Watt_b  = (const float*)d_in[27];
    const float* Wc_w    = (const float*)d_in[28];
    const float* Wc_b    = (const float*)d_in[29];
    const float* Whs_w   = (const float*)d_in[30];
    const float* Whs_b   = (const float*)d_in[31];
    const float* Wop_w   = (const float*)d_in[32];
    const float* Wop_b   = (const float*)d_in[33];
    const float* out1_w  = (const float*)d_in[34];
    const float* out1_b  = (const float*)d_in[35];
    const float* out2_w  = (const float*)d_in[36];
    const float* out2_b  = (const float*)d_in[37];
    const int* l_n   = (const int*)d_in[38];
    const int* l_hpu = (const int*)d_in[39];
    const int* wc    = (const int*)d_in[40];
    const int* wn    = (const int*)d_in[41];
    const int* wo    = (const int*)d_in[42];
    const int* knowledge        = (const int*)d_in[43];
    const int* knowledge_header = (const int*)d_in[44];

    float* ws = (float*)d_ws;
    // ---- workspace map (float offsets; lifetimes annotated) ----
    ushort* proj_q  = (ushort*)(ws + 0);          // [0,12582912)  49152x512 bf16
    ushort* proj_h  = (ushort*)(ws + 12582912);   // [12582912,15728640) 12288x512 bf16
    ushort* AbfH0   = (ushort*)(ws + 15728640);   // wemb_hpu bf16 (dead after G0)
    ushort* A_pad   = (ushort*)(ws + 15728640);   // [49152][192] bf16 (written post-G0)
    ushort* Bp_att  = (ushort*)(ws + 20447232);   // 256x192
    ushort* Bp_out  = (ushort*)(ws + 20471808);   // 128x192
    float*  bias_pad = ws + 20484096;             // 256
    ushort* h_h0_bf = (ushort*)(ws + 22057216);   // 12288x128 bf16
    ushort* WbfQ0   = (ushort*)(ws + 22843648);   // 512x512 bf16
    ushort* WbfH0   = (ushort*)(ws + 22974720);
    ushort* WbfQ1   = (ushort*)(ws + 23105792);   // 512x128
    ushort* WbfH1   = (ushort*)(ws + 23138560);
    uint*   frag8   = (uint*)(ws + 23171328);     // 8 x 4096 dwords int8 Whh
    float*  ksc     = ws + 23204096;              // 8 x 256 scales
    float*  bias_all = ws + 23236864;             // [4][512]
    ushort* AbfQ0   = (ushort*)(ws + 25165824);   // wemb_n bf16 (dead after G0)
    float*  h1_head = ws + 26738688;              // 12288x128 fp32 (post-G0)
    ushort* wenc0_bf = (ushort*)(ws + 31457280);  // 49152x128 bf16 (post-G0)
    float*  attx    = ws + 0;                     // reuse proj_q after QS1
    float*  npart   = ws + 6488064;               // [6488064,12779520)
    float*  hs_ob   = ws + 38541312;
    float*  vec     = ws + 38645760;
    float*  vpart   = ws + 38793216;
    float*  outp    = (float*)d_out;

    dim3 blk(256);
    auto cast2 = [&](const float* a, const float* b, ushort* oa, ushort* ob, int na, int nb) {
        cast2_bf16_kernel<<<dim3(((na + nb) / 8 + 255) / 256), blk, 0, stream>>>(a, b, oa, ob, na, nb);
    };

    // ---- prep + casts ----
    prep_all_kernel<<<dim3(401), blk, 0, stream>>>(
        Whh_n0f, Whh_n0b, Whh_n1f, Whh_n1b, Whh_h0f, Whh_h0b, Whh_h1f, Whh_h1b,
        frag8, ksc,
        b_n0f, b_n0b, b_n1f, b_n1b, b_h0f, b_h0b, b_h1f, b_h1b, bias_all,
        Watt_w, Bp_att, out1_w, Bp_out, Watt_b, bias_pad);
    cast2(wemb_n, wemb_hpu, AbfQ0, AbfH0, 96 * 512 * 512, 1536 * 8 * 512);
    cast2(Wih_n0f, Wih_n0b, WbfQ0, WbfQ0 + 256 * 512, 256 * 512, 256 * 512);
    cast2(Wih_h0f, Wih_h0b, WbfH0, WbfH0 + 256 * 512, 256 * 512, 256 * 512);
    cast2(Wih_n1f, Wih_n1b, WbfQ1, WbfQ1 + 256 * 128, 256 * 128, 256 * 128);
    cast2(Wih_h1f, Wih_h1b, WbfH1, WbfH1 + 256 * 128, 256 * 128, 256 * 128);

    // ---- layer 0 projections (QG0 + HG0 in one dispatch) ----
    gemm_dual_kernel<<<dim3(4, 480), blk, 0, stream>>>(
        AbfQ0, WbfQ0, bias_all + 0 * 512, proj_q, 384,
        AbfH0, WbfH0, bias_all + 2 * 512, proj_h,
        512, 512, 512, 2);
    onehot_pad_kernel<<<dim3(192), blk, 0, stream>>>(knowledge, A_pad);

    // ---- layer-0 scans ----
    lstm_scan_i8<1><<<dim3(96, 2), dim3(64), 0, stream>>>(
        proj_q, frag8 + 0 * 4096, frag8 + 1 * 4096, ksc + 0 * 256, ksc + 1 * 256,
        l_n, wenc0_bf, 512, 128);
    lstm_scan_i8<1><<<dim3(1536, 2), dim3(64), 0, stream>>>(
        proj_h, frag8 + 4 * 4096, frag8 + 5 * 4096, ksc + 4 * 256, ksc + 5 * 256,
        l_hpu, h_h0_bf, 8, 128);

    // ---- layer 1 projections (QG1 + HG1 in one dispatch) ----
    gemm_dual_kernel<<<dim3(4, 480), blk, 0, stream>>>(
        wenc0_bf, WbfQ1, bias_all + 1 * 512, proj_q, 384,
        h_h0_bf, WbfH1, bias_all + 3 * 512, proj_h,
        128, 512, 512, 2);

    // ---- layer-1 scans: QS1 writes A_pad bf16 directly (cols 0..127, stride 192) ----
    lstm_scan_i8<1><<<dim3(96, 2), dim3(64), 0, stream>>>(
        proj_q, frag8 + 2 * 4096, frag8 + 3 * 4096, ksc + 2 * 256, ksc + 3 * 256,
        l_n, A_pad, 512, 192);
    lstm_scan_i8<0><<<dim3(1536, 2), dim3(64), 0, stream>>>(
        proj_h, frag8 + 6 * 4096, frag8 + 7 * 4096, ksc + 6 * 256, ksc + 7 * 256,
        l_hpu, h1_head, 8, 128);

    // ---- tail ----
    hs_merge_kernel<<<dim3(96), blk, 0, stream>>>(h1_head, l_hpu, knowledge_header,
                                                  wc, wn, hs_ob);
    gemm_pair_kernel<<<dim3(3, 384), blk, 0, stream>>>(
        A_pad, Bp_att, bias_pad, attx, Bp_out, npart, 192);
    att_vec_kernel<<<dim3(96, 4), blk, 0, stream>>>(attx, hs_ob, A_pad, l_n,
                                                    Wc_w, Wc_b, Whs_w, Whs_b,
                                                    Wop_w, Wop_b, wn, wo, vec);
    gemm_bias_kernel<<<dim3(2, 6), blk, 0, stream>>>(vec, out1_w, out1_b, vpart,
                                                     384, 128, 384, 384, 524, 128);
    final_kernel<<<dim3(2, 96), blk, 0, stream>>>(vpart, npart, out2_w, out2_b, l_n, outp);
}

// Round 16
// 655.139 us; speedup vs baseline: 1.1148x; 1.0455x over previous
//
#include <hip/hip_runtime.h>
#include <math.h>

#define NEGV -1e10f

typedef __bf16 bf16x8 __attribute__((ext_vector_type(8)));
typedef float f32x4 __attribute__((ext_vector_type(4)));
typedef unsigned short ushort;
typedef unsigned int uint;

__device__ __forceinline__ float fast_tanh(float x) {
    float e = __expf(2.0f * x);
    return fmaf(-2.f, __builtin_amdgcn_rcpf(e + 1.f), 1.f);
}
__device__ __forceinline__ float fast_sig(float x) {
    return __builtin_amdgcn_rcpf(1.f + __expf(-x));
}
__device__ __forceinline__ ushort f2bf(float x) {
    unsigned int b = __float_as_uint(x);
    b += 0x7fffu + ((b >> 16) & 1u);   // RNE
    return (ushort)(b >> 16);
}
#if __has_builtin(__builtin_amdgcn_sdot4)
#define SDOT4(a, b, c) __builtin_amdgcn_sdot4((int)(a), (int)(b), (int)(c), false)
#else
__device__ __forceinline__ int SDOT4(int a, int b, int c) {
    #pragma unroll
    for (int k = 0; k < 4; k++) {
        int xa = (a >> (8 * k)) & 0xff; xa = (xa ^ 0x80) - 0x80;
        int xb = (b >> (8 * k)) & 0xff; xb = (xb ^ 0x80) - 0x80;
        c += xa * xb;
    }
    return c;
}
#endif
// VALU-pipe lane swaps within quads: quad_perm[1,0,3,2]=0xB1 (lane^1),
// quad_perm[2,3,0,1]=0x4E (lane^2)
__device__ __forceinline__ int dpp_xor1(int v) {
    return __builtin_amdgcn_update_dpp(0, v, 0xB1, 0xf, 0xf, true);
}
__device__ __forceinline__ int dpp_xor2(int v) {
    return __builtin_amdgcn_update_dpp(0, v, 0x4E, 0xf, 0xf, true);
}
// async 16B global -> LDS (dest = wave-uniform base + lane*16, src per-lane)
__device__ __forceinline__ void async16(void* l, const void* g) {
    __builtin_amdgcn_global_load_lds(
        (const __attribute__((address_space(1))) void*)g,
        (__attribute__((address_space(3))) void*)l,
        16, 0, 0);
}

// ---------------- dual fp32 -> bf16 cast (both n % 8 == 0) ----------------
__global__ __launch_bounds__(256) void cast2_bf16_kernel(
    const float* __restrict__ inA, const float* __restrict__ inB,
    ushort* __restrict__ outA, ushort* __restrict__ outB, int nA, int nB)
{
    int i = (blockIdx.x * 256 + threadIdx.x) * 8;
    const float* in;
    ushort* out;
    if (i < nA) { in = inA; out = outA; }
    else {
        i -= nA;
        if (i >= nB) return;
        in = inB; out = outB;
    }
    float4 a = *(const float4*)(in + i);
    float4 b = *(const float4*)(in + i + 4);
    uint4 o;
    o.x = (unsigned)f2bf(a.x) | ((unsigned)f2bf(a.y) << 16);
    o.y = (unsigned)f2bf(a.z) | ((unsigned)f2bf(a.w) << 16);
    o.z = (unsigned)f2bf(b.x) | ((unsigned)f2bf(b.y) << 16);
    o.w = (unsigned)f2bf(b.z) | ((unsigned)f2bf(b.w) << 16);
    *(uint4*)(out + i) = o;
}

// ============ prep_all: whh-int8 pack | bias concat | Bp_att | Bp_out | bias_pad ============
// blocks [0,8): per-mat int8 pack, LDS-staging layout (chunk-major, lane-consecutive):
//   dword j = g*16+jj of lane l -> frag8[mat*4096 + (j>>2)*256 + l*4 + (j&3)]
//   ksc[mat*256 + l*4 + g] = (amax/127)/127
// blocks [8,16): bias_all; [16,272): Bp_att rows; [272,400): Bp_out rows; 400: bias_pad
__global__ __launch_bounds__(256) void prep_all_kernel(
    const float* W0, const float* W1, const float* W2, const float* W3,
    const float* W4, const float* W5, const float* W6, const float* W7,
    uint* __restrict__ frag8, float* __restrict__ ksc,
    const float* s0, const float* s1, const float* s2, const float* s3,
    const float* s4, const float* s5, const float* s6, const float* s7,
    float* __restrict__ bias_all,
    const float* __restrict__ Watt_w, ushort* __restrict__ Bp_att,
    const float* __restrict__ out1_w, ushort* __restrict__ Bp_out,
    const float* __restrict__ Watt_b, float* __restrict__ bias_pad)
{
    const int bx = blockIdx.x, tid = threadIdx.x;
    if (bx < 8) {
        const float* Ws[8] = {W0, W1, W2, W3, W4, W5, W6, W7};
        const float* W = Ws[bx];
        int l = tid >> 2, g = tid & 3;
        const float* row = W + (size_t)(g * 64 + l) * 64;
        float amax = 0.f;
        for (int k = 0; k < 64; k++) amax = fmaxf(amax, fabsf(row[k]));
        float sw = fmaxf(amax, 1e-12f) / 127.f;
        float inv = 127.f / fmaxf(amax, 1e-12f);
        ksc[bx * 256 + l * 4 + g] = sw / 127.f;
        for (int jj = 0; jj < 16; jj++) {
            uint wd = 0;
            #pragma unroll
            for (int k = 0; k < 4; k++) {
                int q = __float2int_rn(row[4 * jj + k] * inv);
                q = max(-127, min(127, q));
                wd |= ((uint)(q & 0xff)) << (8 * k);
            }
            int j = g * 16 + jj;
            frag8[bx * 4096 + (j >> 2) * 256 + l * 4 + (j & 3)] = wd;
        }
    } else if (bx < 16) {
        const float* srcs[8] = {s0, s1, s2, s3, s4, s5, s6, s7};
        bias_all[(bx - 8) * 256 + tid] = srcs[bx - 8][tid];
    } else if (bx < 272) {
        int rowi = bx - 16;
        if (tid < 96) {
            float a = 0.f, b = 0.f;
            if (rowi < 132) {
                const float* s = Watt_w + (size_t)rowi * 140;
                if (2 * tid < 140) a = s[2 * tid];
                if (2 * tid + 1 < 140) b = s[2 * tid + 1];
            }
            ((uint*)(Bp_att + (size_t)rowi * 192))[tid] =
                (uint)f2bf(a) | ((uint)f2bf(b) << 16);
        }
    } else if (bx < 400) {
        int rowi = bx - 272;
        if (tid < 96) {
            const float* s = out1_w + (size_t)rowi * 524 + 384;
            float a = (2 * tid < 140) ? s[2 * tid] : 0.f;
            float b = (2 * tid + 1 < 140) ? s[2 * tid + 1] : 0.f;
            ((uint*)(Bp_out + (size_t)rowi * 192))[tid] =
                (uint)f2bf(a) | ((uint)f2bf(b) << 16);
        }
    } else {
        bias_pad[tid] = (tid < 132) ? Watt_b[tid] : 0.f;
    }
}

// =============== shared MFMA GEMM core: C = A[.,K]bf16 @ B[.,K]bf16^T (+bias) ===============
// mode 1: fp32 store, cols < Nstore. mode 2: bf16 store, scan-perm layout
// (col = dir*256+g*64+u -> dir*256 + u*4 + g), ldc elements.
__device__ __forceinline__ void gemm_core(
    const ushort* __restrict__ A, const ushort* __restrict__ B,
    const float* __restrict__ bias, void* __restrict__ C,
    int K, int ldc, int Nstore, int mode, int bm, int bn, ushort* lds)
{
    ushort* ldsA = lds;
    ushort* ldsB = lds + 8192;
    const int tid = threadIdx.x;
    const int wv = tid >> 6, ln = tid & 63;
    const int r15 = ln & 15, r4 = ln >> 4;

    f32x4 acc[4][4] = {};

    for (int k0 = 0; k0 < K; k0 += 64) {
        #pragma unroll
        for (int c4 = 0; c4 < 4; c4++) {
            const int c = c4 * 4 + wv;
            const int s = c * 64 + ln;
            const int rt = s >> 3;
            const int ce = ((s & 7) ^ (rt & 7)) * 8;   // T2 swizzle (both sides)
            async16(&ldsA[c * 512], A + (size_t)(bm + rt) * K + k0 + ce);
            async16(&ldsB[c * 512], B + (size_t)(bn + rt) * K + k0 + ce);
        }
        __syncthreads();
        const int mr = (wv >> 1) * 64, nc = (wv & 1) * 64;
        #pragma unroll
        for (int kk = 0; kk < 2; kk++) {
            bf16x8 af[4], bfr[4];
            #pragma unroll
            for (int m = 0; m < 4; m++) {
                const int r = mr + m * 16 + r15;
                const int off = r * 128 + ((kk * 64 + r4 * 16) ^ ((r & 7) << 4));
                af[m] = *(const bf16x8*)((const char*)ldsA + off);
            }
            #pragma unroll
            for (int n = 0; n < 4; n++) {
                const int r = nc + n * 16 + r15;
                const int off = r * 128 + ((kk * 64 + r4 * 16) ^ ((r & 7) << 4));
                bfr[n] = *(const bf16x8*)((const char*)ldsB + off);
            }
            #pragma unroll
            for (int m = 0; m < 4; m++)
                #pragma unroll
                for (int n = 0; n < 4; n++)
                    acc[m][n] = __builtin_amdgcn_mfma_f32_16x16x32_bf16(
                        af[m], bfr[n], acc[m][n], 0, 0, 0);
        }
        __syncthreads();
    }
    const int mro = bm + (wv >> 1) * 64, nco = bn + (wv & 1) * 64;
    #pragma unroll
    for (int m = 0; m < 4; m++) {
        #pragma unroll
        for (int n = 0; n < 4; n++) {
            const int col = nco + n * 16 + r15;
            const float bs = bias ? bias[col] : 0.f;
            if (mode == 2) {
                const int cout = (col >> 8) * 256 + (col & 63) * 4 + ((col >> 6) & 3);
                #pragma unroll
                for (int r = 0; r < 4; r++) {
                    const int row = mro + m * 16 + r4 * 4 + r;
                    ((ushort*)C)[(size_t)row * ldc + cout] = f2bf(acc[m][n][r] + bs);
                }
            } else if (col < Nstore) {
                #pragma unroll
                for (int r = 0; r < 4; r++) {
                    const int row = mro + m * 16 + r4 * 4 + r;
                    ((float*)C)[(size_t)row * ldc + col] = acc[m][n][r] + bs;
                }
            }
        }
    }
}

// dual-segment GEMM: blockIdx.y < My0 -> segment 0, else segment 1
__global__ __launch_bounds__(256) void gemm_dual_kernel(
    const ushort* A0, const ushort* B0, const float* b0, void* C0, int My0,
    const ushort* A1, const ushort* B1, const float* b1, void* C1,
    int K, int ldc, int Nstore, int mode)
{
    __shared__ __align__(16) ushort smem[16384];
    int by = blockIdx.y;
    if (by < My0)
        gemm_core(A0, B0, b0, C0, K, ldc, Nstore, mode, by * 128, blockIdx.x * 128, smem);
    else
        gemm_core(A1, B1, b1, C1, K, ldc, Nstore, mode, (by - My0) * 128, blockIdx.x * 128, smem);
}

// pair GEMM: bx<2 -> attx (N=132 fp32), bx==2 -> npart (N=128 fp32); shared A
__global__ __launch_bounds__(256) void gemm_pair_kernel(
    const ushort* __restrict__ A,
    const ushort* __restrict__ B0, const float* __restrict__ b0, float* __restrict__ C0,
    const ushort* __restrict__ B1, float* __restrict__ C1, int K)
{
    __shared__ __align__(16) ushort smem[16384];
    if (blockIdx.x < 2)
        gemm_core(A, B0, b0, C0, K, 132, 132, 1, blockIdx.y * 128, blockIdx.x * 128, smem);
    else
        gemm_core(A, B1, nullptr, C1, K, 128, 128, 1, blockIdx.y * 128, 0, smem);
}

// =============== LSTM scan int8 core: one wave per (chain,dir) ===============
// Weights staged ONCE into LDS (16KB, global_load_lds) and re-read each step via
// conflict-free ds_read_b128 on the DS pipe. This retries R14's LDS staging with
// R15's DPP swaps: the DS pipe now serves ONLY weight reads (R14's regression was
// ds_read colliding with shfl ds_swizzles; swaps are now VALU DPP). proj prefetch
// on VMEM; dots/gates/redistr on VALU. Per-row int8 quant, scale ksc[l*4+g].
// proj bf16 [ch][T][dir*256 + u*4 + g]; OBF=1: bf16 out (os elems), else fp32.
template<int OBF>
__device__ __forceinline__ void scan_core(
    const ushort* __restrict__ proj,
    const uint* __restrict__ frag_f, const uint* __restrict__ frag_b,
    const float* __restrict__ ksc_f, const float* __restrict__ ksc_b,
    const int* __restrict__ lengths, void* __restrict__ out,
    int T, int os, int ch, int dir, uint* wlds)
{
    const int l = threadIdx.x;
    const int L = lengths[ch];
    const ushort* projc = proj + (size_t)ch * T * 512 + dir * 256;
    const uint* fragm = dir ? frag_b : frag_f;
    const float4 ks = *(const float4*)((dir ? ksc_b : ksc_f) + l * 4);

    // stage 16KB weights into LDS (chunk-major, lane-consecutive 16B)
    #pragma unroll
    for (int c = 0; c < 16; c++)
        async16(&wlds[c * 256], fragm + c * 256 + l * 4);
    asm volatile("s_waitcnt vmcnt(0)" ::: "memory");

    int hs[16];
    #pragma unroll
    for (int i = 0; i < 16; i++) hs[i] = 0;

    float cst = 0.f;
    const long od = dir ? -(long)os : (long)os;
    const size_t obase = (size_t)ch * T * os
                       + (size_t)(dir ? (L - 1) : 0) * os + dir * 64 + l;
    float* orow_f = (float*)out + obase;
    ushort* orow_h = (ushort*)out + obase;

    auto ld = [&](int s) -> uint2 {
        int tc = (s < L) ? s : (L - 1);
        int t = dir ? (L - 1 - tc) : tc;
        return *(const uint2*)(projc + (size_t)t * 512 + 4 * l);
    };
    uint2 P0 = ld(0), P1 = ld(1), P2 = ld(2);

    for (int s = 0; s < L; s++) {
        int ai0 = 0, ai1 = 0, af0 = 0, af1 = 0;
        int ag0 = 0, ag1 = 0, ao0 = 0, ao1 = 0;
        #pragma unroll
        for (int c = 0; c < 4; c++) {
            uint4 wi = *(const uint4*)&wlds[(0  + c) * 256 + l * 4];
            uint4 wf = *(const uint4*)&wlds[(4  + c) * 256 + l * 4];
            uint4 wg = *(const uint4*)&wlds[(8  + c) * 256 + l * 4];
            uint4 wo = *(const uint4*)&wlds[(12 + c) * 256 + l * 4];
            const int h0 = hs[c * 4 + 0], h1 = hs[c * 4 + 1];
            const int h2 = hs[c * 4 + 2], h3 = hs[c * 4 + 3];
            ai0 = SDOT4(wi.x, h0, ai0); ai1 = SDOT4(wi.y, h1, ai1);
            ai0 = SDOT4(wi.z, h2, ai0); ai1 = SDOT4(wi.w, h3, ai1);
            af0 = SDOT4(wf.x, h0, af0); af1 = SDOT4(wf.y, h1, af1);
            af0 = SDOT4(wf.z, h2, af0); af1 = SDOT4(wf.w, h3, af1);
            ag0 = SDOT4(wg.x, h0, ag0); ag1 = SDOT4(wg.y, h1, ag1);
            ag0 = SDOT4(wg.z, h2, ag0); ag1 = SDOT4(wg.w, h3, ag1);
            ao0 = SDOT4(wo.x, h0, ao0); ao1 = SDOT4(wo.y, h1, ao1);
            ao0 = SDOT4(wo.z, h2, ao0); ao1 = SDOT4(wo.w, h3, ao1);
        }
        const float pi = __uint_as_float(P0.x << 16);
        const float pf = __uint_as_float(P0.x & 0xffff0000u);
        const float pg = __uint_as_float(P0.y << 16);
        const float po = __uint_as_float(P0.y & 0xffff0000u);
        const float iv = fast_sig(fmaf((float)(ai0 + ai1), ks.x, pi));
        const float fv = fast_sig(fmaf((float)(af0 + af1), ks.y, pf));
        const float gv = fast_tanh(fmaf((float)(ag0 + ag1), ks.z, pg));
        const float ov = fast_sig(fmaf((float)(ao0 + ao1), ks.w, po));
        cst = fmaf(fv, cst, iv * gv);
        const float hv = ov * fast_tanh(cst);

        if (OBF) { *orow_h = f2bf(hv); orow_h += od; }
        else     { *orow_f = hv;       orow_f += od; }

        // h -> int8, pack 4 lanes/dword via 2 DPP quad_perm swaps (VALU pipe),
        // then 16 readlane -> SGPR broadcast
        int q8 = __float2int_rn(hv * 127.f);
        int b = q8 & 0xff;
        int t1 = dpp_xor1(b);
        int v01 = (l & 1) ? (t1 | (b << 8)) : (b | (t1 << 8));
        int t2 = dpp_xor2(v01);
        int v0123 = (l & 2) ? ((t2 & 0xffff) | (v01 << 16))
                            : ((v01 & 0xffff) | (t2 << 16));
        #pragma unroll
        for (int i = 0; i < 16; i++)
            hs[i] = __builtin_amdgcn_readlane(v0123, 4 * i);

        P0 = P1; P1 = P2; P2 = ld(s + 3);
    }

    // zero-fill masked region t in [L, T), this direction's 64 cols
    if (OBF) {
        ushort* ob = (ushort*)out + (size_t)ch * T * os + dir * 64;
        for (int idx = l; idx < (T - L) * 64; idx += 64) {
            int t = L + (idx >> 6);
            ob[(size_t)t * os + (idx & 63)] = 0;
        }
    } else {
        float* ob = (float*)out + (size_t)ch * T * os + dir * 64;
        for (int idx = l; idx < (T - L) * 64; idx += 64) {
            int t = L + (idx >> 6);
            ob[(size_t)t * os + (idx & 63)] = 0.f;
        }
    }
}

// fused dual-segment scans (scan||scan: both latency-bound 64-thread waves; NOT
// the R8 scan||GEMM mistake): bx < nA -> segment A (question), else B (header).
template<int OBFA, int OBFB>
__global__ __launch_bounds__(64, 1) void scan_fused_kernel(
    int nA,
    const ushort* projA, const uint* fAf, const uint* fAb,
    const float* kAf, const float* kAb, const int* lenA, void* outA, int TA, int osA,
    const ushort* projB, const uint* fBf, const uint* fBb,
    const float* kBf, const float* kBb, const int* lenB, void* outB, int TB, int osB)
{
    __shared__ __align__(16) uint wlds[4096];
    const int bx = blockIdx.x, dir = blockIdx.y;
    if (bx < nA)
        scan_core<OBFA>(projA, fAf, fAb, kAf, kAb, lenA, outA, TA, osA, bx, dir, wlds);
    else
        scan_core<OBFB>(projB, fBf, fBb, kBf, kBb, lenB, outB, TB, osB, bx - nA, dir, wlds);
}

// ---------------- one-hot + zero pad into A_pad cols 128..191 (bf16) ----------------
__global__ __launch_bounds__(256) void onehot_pad_kernel(
    const int* __restrict__ knowledge, ushort* __restrict__ A_pad)
{
    int row = blockIdx.x * 256 + threadIdx.x;
    if (row >= 96 * 512) return;
    int kn = knowledge[row];
    uint words[8] = {0, 0, 0, 0, 0, 0, 0, 0};
    words[kn >> 1] = (kn & 1) ? 0x3F800000u : 0x00003F80u;   // bf16 1.0
    uint4* dst = (uint4*)(A_pad + (size_t)row * 192 + 128);
    dst[0] = make_uint4(words[0], words[1], words[2], words[3]);
    dst[1] = make_uint4(words[4], words[5], words[6], words[7]);
    uint4 z = make_uint4(0, 0, 0, 0);
    dst[2] = z; dst[3] = z; dst[4] = z; dst[5] = z; dst[6] = z; dst[7] = z;
}

// ---------------- header select + gather: wenc_hs in smem -> hs_ob ----------------
__global__ __launch_bounds__(256) void hs_merge_kernel(
    const float* __restrict__ h1_head, const int* __restrict__ l_hpu,
    const int* __restrict__ knowledge_header,
    const int* __restrict__ wc, const int* __restrict__ wn,
    float* __restrict__ hs_ob)
{
    int b = blockIdx.x, tid = threadIdx.x;
    __shared__ float whs[16][132];
    for (int idx = tid; idx < 16 * 132; idx += 256) {
        int u = idx / 132, c = idx - u * 132;
        int g = b * 16 + u;
        int L = l_hpu[g];
        float v;
        if (c < 128) v = h1_head[((size_t)g * 8 + (L - 1)) * 128 + c];
        else v = ((c - 128) == knowledge_header[g]) ? 1.f : 0.f;
        whs[u][c] = v;
    }
    __syncthreads();
    for (int idx = tid; idx < 4 * 132; idx += 256) {
        int w = idx / 132, c = idx - w * 132;
        int col = (w < wn[b]) ? wc[b * 4 + w] : 0;
        hs_ob[((size_t)b * 4 + w) * 132 + c] = whs[col][c];
    }
}

// ------- fused attention: scores(attx) -> softmax -> context(A_pad) -> vec -------
__global__ __launch_bounds__(256) void att_vec_kernel(
    const float* __restrict__ attx, const float* __restrict__ hs_ob,
    const ushort* __restrict__ A_pad, const int* __restrict__ l_n,
    const float* __restrict__ Wc_w, const float* __restrict__ Wc_b,
    const float* __restrict__ Whs_w, const float* __restrict__ Whs_b,
    const float* __restrict__ Wop_w, const float* __restrict__ Wop_b,
    const int* __restrict__ wn, const int* __restrict__ wo,
    float* __restrict__ vec)
{
    int b = blockIdx.x, w = blockIdx.y;
    int tid = threadIdx.x;
    int L = l_n[b];
    __shared__ float q[132];
    __shared__ float sc[512];
    __shared__ float red[256];
    __shared__ float cn[140];
    if (tid < 132) q[tid] = hs_ob[((size_t)b * 4 + w) * 132 + tid];
    __syncthreads();
    for (int t = tid; t < 512; t += 256) {
        float s = -1e30f;
        if (t < L) {
            const float* ax = attx + ((size_t)b * 512 + t) * 132;
            float s0 = 0.f, s1 = 0.f, s2 = 0.f, s3 = 0.f;
            #pragma unroll
            for (int d = 0; d < 132; d += 4) {
                s0 = fmaf(ax[d + 0], q[d + 0], s0);
                s1 = fmaf(ax[d + 1], q[d + 1], s1);
                s2 = fmaf(ax[d + 2], q[d + 2], s2);
                s3 = fmaf(ax[d + 3], q[d + 3], s3);
            }
            s = (s0 + s1) + (s2 + s3);
        }
        sc[t] = s;
    }
    __syncthreads();
    red[tid] = fmaxf(sc[tid], sc[tid + 256]);
    __syncthreads();
    for (int off = 128; off > 0; off >>= 1) {
        if (tid < off) red[tid] = fmaxf(red[tid], red[tid + off]);
        __syncthreads();
    }
    float m = red[0];
    __syncthreads();
    float ps = 0.f;
    for (int t = tid; t < 512; t += 256) {
        float e = (t < L) ? __expf(sc[t] - m) : 0.f;
        sc[t] = e;
        ps += e;
    }
    red[tid] = ps;
    __syncthreads();
    for (int off = 128; off > 0; off >>= 1) {
        if (tid < off) red[tid] += red[tid + off];
        __syncthreads();
    }
    float inv = 1.f / red[0];
    if (tid < 140) {
        float acc = 0.f;
        const ushort* col = A_pad + (size_t)b * 512 * 192 + tid;
        for (int t = 0; t < L; t++)
            acc = fmaf(sc[t], __uint_as_float((uint)col[(size_t)t * 192] << 16), acc);
        cn[tid] = acc * inv;
    }
    __syncthreads();
    float* vrow = vec + ((size_t)b * 4 + w) * 384;
    if (tid < 128) {
        float acc = Wc_b[tid];
        const float* r = Wc_w + (size_t)tid * 140;
        for (int d = 0; d < 140; d++) acc = fmaf(r[d], cn[d], acc);
        vrow[tid] = acc;
    } else {
        int jj = tid - 128;
        float acc = Whs_b[jj];
        const float* r = Whs_w + (size_t)jj * 132;
        for (int d = 0; d < 132; d++) acc = fmaf(r[d], q[d], acc);
        vrow[128 + jj] = acc;
    }
    if (tid < 128) {
        int op = (w < wn[b]) ? wo[b * 4 + w] : 0;
        vrow[256 + tid] = Wop_b[tid] + Wop_w[tid * 4 + op];
    }
}

// ---------------- SIMT GEMM (vpart): C = A @ B^T (+bias) ----------------
__global__ __launch_bounds__(256) void gemm_bias_kernel(
    const float* __restrict__ A, const float* __restrict__ B,
    const float* __restrict__ bias, float* __restrict__ C,
    int M, int N, int K, int lda, int ldb, int ldc)
{
    __shared__ float As[16][68];
    __shared__ float Bs[16][68];
    const int tid = threadIdx.x;
    const int bm = blockIdx.y * 64;
    const int bn = blockIdx.x * 64;
    const int tx = tid & 15;
    const int ty = tid >> 4;
    const int lm = tid & 63;
    const int lk = (tid >> 6) << 2;
    float acc[4][4] = {};
    const int arow = bm + lm;
    const int brow = bn + lm;

    for (int k0 = 0; k0 < K; k0 += 16) {
        int k = k0 + lk;
        float4 av = make_float4(0.f, 0.f, 0.f, 0.f);
        float4 bv = make_float4(0.f, 0.f, 0.f, 0.f);
        if (arow < M) {
            if (k + 4 <= K) av = *(const float4*)(A + (size_t)arow * lda + k);
            else { float* p = (float*)&av;
                for (int i = 0; i < 4; i++) if (k + i < K) p[i] = A[(size_t)arow * lda + k + i]; }
        }
        if (brow < N) {
            if (k + 4 <= K) bv = *(const float4*)(B + (size_t)brow * ldb + k);
            else { float* p = (float*)&bv;
                for (int i = 0; i < 4; i++) if (k + i < K) p[i] = B[(size_t)brow * ldb + k + i]; }
        }
        As[lk + 0][lm] = av.x; As[lk + 1][lm] = av.y; As[lk + 2][lm] = av.z; As[lk + 3][lm] = av.w;
        Bs[lk + 0][lm] = bv.x; Bs[lk + 1][lm] = bv.y; Bs[lk + 2][lm] = bv.z; Bs[lk + 3][lm] = bv.w;
        __syncthreads();
        #pragma unroll
        for (int kk = 0; kk < 16; kk++) {
            float a[4], bb[4];
            #pragma unroll
            for (int i = 0; i < 4; i++) a[i] = As[kk][ty * 4 + i];
            #pragma unroll
            for (int j = 0; j < 4; j++) bb[j] = Bs[kk][tx * 4 + j];
            #pragma unroll
            for (int i = 0; i < 4; i++)
                #pragma unroll
                for (int j = 0; j < 4; j++)
                    acc[i][j] = fmaf(a[i], bb[j], acc[i][j]);
        }
        __syncthreads();
    }
    #pragma unroll
    for (int i = 0; i < 4; i++) {
        int row = bm + ty * 4 + i;
        if (row >= M) continue;
        #pragma unroll
        for (int j = 0; j < 4; j++) {
            int col = bn + tx * 4 + j;
            if (col < N) C[(size_t)row * ldc + col] = acc[i][j] + (bias ? bias[col] : 0.f);
        }
    }
}

// ---------------- final: out[b,w,t,:] = tanh(vpart+npart)@out2.T + b, masked ----------------
__global__ __launch_bounds__(256) void final_kernel(
    const float* __restrict__ vpart, const float* __restrict__ npart,
    const float* __restrict__ out2_w, const float* __restrict__ out2_b,
    const int* __restrict__ l_n, float* __restrict__ out)
{
    int b = blockIdx.y;
    int tid = threadIdx.x;
    int t = blockIdx.x * 256 + tid;
    __shared__ float vp[512];
    __shared__ float w2[256];
    w2[tid] = out2_w[tid];
    for (int i = tid; i < 512; i += 256) vp[i] = vpart[(size_t)b * 512 + i];
    __syncthreads();
    int L = l_n[b];
    float s[4][2];
    if (t < L) {
        float b0 = out2_b[0], b1 = out2_b[1];
        #pragma unroll
        for (int w = 0; w < 4; w++) { s[w][0] = b0; s[w][1] = b1; }
        const float4* np4 = (const float4*)(npart + ((size_t)b * 512 + t) * 128);
        for (int h4 = 0; h4 < 32; h4++) {
            float4 n = np4[h4];
            const float* nf = (const float*)&n;
            #pragma unroll
            for (int e = 0; e < 4; e++) {
                int h = h4 * 4 + e;
                float nv = nf[e];
                float w0 = w2[h], w1 = w2[128 + h];
                #pragma unroll
                for (int w = 0; w < 4; w++) {
                    float z = fast_tanh(vp[w * 128 + h] + nv);
                    s[w][0] = fmaf(z, w0, s[w][0]);
                    s[w][1] = fmaf(z, w1, s[w][1]);
                }
            }
        }
    } else {
        #pragma unroll
        for (int w = 0; w < 4; w++) { s[w][0] = NEGV; s[w][1] = NEGV; }
    }
    #pragma unroll
    for (int w = 0; w < 4; w++) {
        size_t o = (((size_t)b * 4 + w) * 512 + t) * 2;
        out[o + 0] = s[w][0];
        out[o + 1] = s[w][1];
    }
}

// ---------------------------------------------------------------------------
extern "C" void kernel_launch(void* const* d_in, const int* in_sizes, int n_in,
                              void* d_out, int out_size, void* d_ws, size_t ws_size,
                              hipStream_t stream)
{
    const float* wemb_n   = (const float*)d_in[0];
    const float* wemb_hpu = (const float*)d_in[1];
    const float* Wih_n0f = (const float*)d_in[2];
    const float* Whh_n0f = (const float*)d_in[3];
    const float* b_n0f   = (const float*)d_in[4];
    const float* Wih_n0b = (const float*)d_in[5];
    const float* Whh_n0b = (const float*)d_in[6];
    const float* b_n0b   = (const float*)d_in[7];
    const float* Wih_n1f = (const float*)d_in[8];
    const float* Whh_n1f = (const float*)d_in[9];
    const float* b_n1f   = (const float*)d_in[10];
    const float* Wih_n1b = (const float*)d_in[11];
    const float* Whh_n1b = (const float*)d_in[12];
    const float* b_n1b   = (const float*)d_in[13];
    const float* Wih_h0f = (const float*)d_in[14];
    const float* Whh_h0f = (const float*)d_in[15];
    const float* b_h0f   = (const float*)d_in[16];
    const float* Wih_h0b = (const float*)d_in[17];
    const float* Whh_h0b = (const float*)d_in[18];
    const float* b_h0b   = (const float*)d_in[19];
    const float* Wih_h1f = (const float*)d_in[20];
    const float* Whh_h1f = (const float*)d_in[21];
    const float* b_h1f   = (const float*)d_in[22];
    const float* Wih_h1b = (const float*)d_in[23];
    const float* Whh_h1b = (const float*)d_in[24];
    const float* b_h1b   = (const float*)d_in[25];
    const float* Watt_w  = (const float*)d_in[26];
    const float* Watt_b  = (const float*)d_in[27];
    const float* Wc_w    = (const float*)d_in[28];
    const float* Wc_b    = (const float*)d_in[29];
    const float* Whs_w   = (const float*)d_in[30];
    const float* Whs_b   = (const float*)d_in[31];
    const float* Wop_w   = (const float*)d_in[32];
    const float* Wop_b   = (const float*)d_in[33];
    const float* out1_w  = (const float*)d_in[34];
    const float* out1_b  = (const float*)d_in[35];
    const float* out2_w  = (const float*)d_in[36];
    const float* out2_b  = (const float*)d_in[37];
    const int* l_n   = (const int*)d_in[38];
    const int* l_hpu = (const int*)d_in[39];
    const int* wc    = (const int*)d_in[40];
    const int* wn    = (const int*)d_in[41];
    const int* wo    = (const int*)d_in[42];
    const int* knowledge        = (const int*)d_in[43];
    const int* knowledge_header = (const int*)d_in[44];

    float* ws = (float*)d_ws;
    // ---- workspace map (float offsets; lifetimes annotated) ----
    ushort* proj_q  = (ushort*)(ws + 0);          // [0,12582912)  49152x512 bf16
    ushort* proj_h  = (ushort*)(ws + 12582912);   // [12582912,15728640) 12288x512 bf16
    ushort* AbfH0   = (ushort*)(ws + 15728640);   // wemb_hpu bf16 (dead after G0)
    ushort* A_pad   = (ushort*)(ws + 15728640);   // [49152][192] bf16 (written post-G0)
    ushort* Bp_att  = (ushort*)(ws + 20447232);   // 256x192
    ushort* Bp_out  = (ushort*)(ws + 20471808);   // 128x192
    float*  bias_pad = ws + 20484096;             // 256
    ushort* h_h0_bf = (ushort*)(ws + 22057216);   // 12288x128 bf16
    ushort* WbfQ0   = (ushort*)(ws + 22843648);   // 512x512 bf16
    ushort* WbfH0   = (ushort*)(ws + 22974720);
    ushort* WbfQ1   = (ushort*)(ws + 23105792);   // 512x128
    ushort* WbfH1   = (ushort*)(ws + 23138560);
    uint*   frag8   = (uint*)(ws + 23171328);     // 8 x 4096 dwords int8 Whh (LDS-tiled)
    float*  ksc     = ws + 23204096;              // 8 x 256 scales
    float*  bias_all = ws + 23236864;             // [4][512]
    ushort* AbfQ0   = (ushort*)(ws + 25165824);   // wemb_n bf16 (dead after G0)
    float*  h1_head = ws + 26738688;              // 12288x128 fp32 (post-G0)
    ushort* wenc0_bf = (ushort*)(ws + 31457280);  // 49152x128 bf16 (post-G0)
    float*  attx    = ws + 0;                     // reuse proj_q after QS1
    float*  npart   = ws + 6488064;               // [6488064,12779520)
    float*  hs_ob   = ws + 38541312;
    float*  vec     = ws + 38645760;
    float*  vpart   = ws + 38793216;
    float*  outp    = (float*)d_out;

    dim3 blk(256);
    auto cast2 = [&](const float* a, const float* b, ushort* oa, ushort* ob, int na, int nb) {
        cast2_bf16_kernel<<<dim3(((na + nb) / 8 + 255) / 256), blk, 0, stream>>>(a, b, oa, ob, na, nb);
    };

    // ---- prep + casts ----
    prep_all_kernel<<<dim3(401), blk, 0, stream>>>(
        Whh_n0f, Whh_n0b, Whh_n1f, Whh_n1b, Whh_h0f, Whh_h0b, Whh_h1f, Whh_h1b,
        frag8, ksc,
        b_n0f, b_n0b, b_n1f, b_n1b, b_h0f, b_h0b, b_h1f, b_h1b, bias_all,
        Watt_w, Bp_att, out1_w, Bp_out, Watt_b, bias_pad);
    cast2(wemb_n, wemb_hpu, AbfQ0, AbfH0, 96 * 512 * 512, 1536 * 8 * 512);
    cast2(Wih_n0f, Wih_n0b, WbfQ0, WbfQ0 + 256 * 512, 256 * 512, 256 * 512);
    cast2(Wih_h0f, Wih_h0b, WbfH0, WbfH0 + 256 * 512, 256 * 512, 256 * 512);
    cast2(Wih_n1f, Wih_n1b, WbfQ1, WbfQ1 + 256 * 128, 256 * 128, 256 * 128);
    cast2(Wih_h1f, Wih_h1b, WbfH1, WbfH1 + 256 * 128, 256 * 128, 256 * 128);

    // ---- layer 0 projections (QG0 + HG0 in one dispatch) ----
    gemm_dual_kernel<<<dim3(4, 480), blk, 0, stream>>>(
        AbfQ0, WbfQ0, bias_all + 0 * 512, proj_q, 384,
        AbfH0, WbfH0, bias_all + 2 * 512, proj_h,
        512, 512, 512, 2);
    onehot_pad_kernel<<<dim3(192), blk, 0, stream>>>(knowledge, A_pad);

    // ---- layer-0 scans: QS0 || HS0 fused ----
    scan_fused_kernel<1, 1><<<dim3(96 + 1536, 2), dim3(64), 0, stream>>>(
        96,
        proj_q, frag8 + 0 * 4096, frag8 + 1 * 4096, ksc + 0 * 256, ksc + 1 * 256,
        l_n, wenc0_bf, 512, 128,
        proj_h, frag8 + 4 * 4096, frag8 + 5 * 4096, ksc + 4 * 256, ksc + 5 * 256,
        l_hpu, h_h0_bf, 8, 128);

    // ---- layer 1 projections (QG1 + HG1 in one dispatch) ----
    gemm_dual_kernel<<<dim3(4, 480), blk, 0, stream>>>(
        wenc0_bf, WbfQ1, bias_all + 1 * 512, proj_q, 384,
        h_h0_bf, WbfH1, bias_all + 3 * 512, proj_h,
        128, 512, 512, 2);

    // ---- layer-1 scans: QS1 (A_pad bf16, stride 192) || HS1 (fp32) fused ----
    scan_fused_kernel<1, 0><<<dim3(96 + 1536, 2), dim3(64), 0, stream>>>(
        96,
        proj_q, frag8 + 2 * 4096, frag8 + 3 * 4096, ksc + 2 * 256, ksc + 3 * 256,
        l_n, A_pad, 512, 192,
        proj_h, frag8 + 6 * 4096, frag8 + 7 * 4096, ksc + 6 * 256, ksc + 7 * 256,
        l_hpu, h1_head, 8, 128);

    // ---- tail ----
    hs_merge_kernel<<<dim3(96), blk, 0, stream>>>(h1_head, l_hpu, knowledge_header,
                                                  wc, wn, hs_ob);
    gemm_pair_kernel<<<dim3(3, 384), blk, 0, stream>>>(
        A_pad, Bp_att, bias_pad, attx, Bp_out, npart, 192);
    att_vec_kernel<<<dim3(96, 4), blk, 0, stream>>>(attx, hs_ob, A_pad, l_n,
                                                    Wc_w, Wc_b, Whs_w, Whs_b,
                                                    Wop_w, Wop_b, wn, wo, vec);
    gemm_bias_kernel<<<dim3(2, 6), blk, 0, stream>>>(vec, out1_w, out1_b, vpart,
                                                     384, 128, 384, 384, 524, 128);
    final_kernel<<<dim3(2, 96), blk, 0, stream>>>(vpart, npart, out2_w, out2_b, l_n, outp);
}